// Round 1
// baseline (460.122 us; speedup 1.0000x reference)
//
#include <hip/hip_runtime.h>
#include <hip/hip_bf16.h>

#define Bc 2
#define Sc 2048
#define Dc 1024
#define Hc 16
#define DHc 64
#define Mc (Bc*Sc)   // 4096

typedef __attribute__((ext_vector_type(8))) short bf16x8;
typedef __attribute__((ext_vector_type(4))) float f32x4;

__device__ __forceinline__ ushort f2bf(float f){
  union { float f; uint32_t u; } c; c.f = f;
  uint32_t u = c.u;
  return (ushort)((u + 0x7fffu + ((u >> 16) & 1u)) >> 16);
}
__device__ __forceinline__ float bf2f(ushort h){
  union { uint32_t u; float f; } c; c.u = ((uint32_t)h) << 16;
  return c.f;
}

// ---------------- transpose + cast: w[K][N] f32 -> wT[N][K] bf16 ----------------
__global__ __launch_bounds__(256) void tcast(const float* __restrict__ w,
                                             ushort* __restrict__ wt,
                                             int K, int N){
  __shared__ float t[32][33];
  int kb = blockIdx.y * 32, nb = blockIdx.x * 32;
  int tx = threadIdx.x & 31, ty = threadIdx.x >> 5;   // ty 0..7
  #pragma unroll
  for (int i = 0; i < 4; i++)
    t[ty + 8*i][tx] = w[(size_t)(kb + ty + 8*i) * N + nb + tx];
  __syncthreads();
  #pragma unroll
  for (int i = 0; i < 4; i++)
    wt[(size_t)(nb + ty + 8*i) * K + kb + tx] = f2bf(t[tx][ty + 8*i]);
}

// ---------------- LayerNorm -> bf16 ----------------
__global__ __launch_bounds__(256) void ln_bf16(const float* __restrict__ x,
                                               const float* __restrict__ g,
                                               const float* __restrict__ b,
                                               ushort* __restrict__ out){
  int row = blockIdx.x;
  const float4 xv = reinterpret_cast<const float4*>(x + (size_t)row * Dc)[threadIdx.x];
  float s  = xv.x + xv.y + xv.z + xv.w;
  float sq = xv.x*xv.x + xv.y*xv.y + xv.z*xv.z + xv.w*xv.w;
  #pragma unroll
  for (int m = 1; m < 64; m <<= 1){ s += __shfl_xor(s, m); sq += __shfl_xor(sq, m); }
  __shared__ float ss[4], ssq[4];
  int wv = threadIdx.x >> 6;
  if ((threadIdx.x & 63) == 0){ ss[wv] = s; ssq[wv] = sq; }
  __syncthreads();
  s  = ss[0] + ss[1] + ss[2] + ss[3];
  sq = ssq[0] + ssq[1] + ssq[2] + ssq[3];
  float mu  = s * (1.0f / Dc);
  float var = sq * (1.0f / Dc) - mu * mu;
  float rstd = rsqrtf(var + 1e-5f);
  float4 gv = reinterpret_cast<const float4*>(g)[threadIdx.x];
  float4 bv = reinterpret_cast<const float4*>(b)[threadIdx.x];
  ushort o[4];
  o[0] = f2bf((xv.x - mu) * rstd * gv.x + bv.x);
  o[1] = f2bf((xv.y - mu) * rstd * gv.y + bv.y);
  o[2] = f2bf((xv.z - mu) * rstd * gv.z + bv.z);
  o[3] = f2bf((xv.w - mu) * rstd * gv.w + bv.w);
  *reinterpret_cast<uint2*>(out + (size_t)row * Dc + threadIdx.x * 4) =
      *reinterpret_cast<uint2*>(o);
}

// ---------------- GEMM: C[M,N] = A[M,K](bf16) @ BT[N,K]^T(bf16) + bias, epilogues ----------------
// EPI 0: qkv scatter -> q/k/v [B*H][S][DH] bf16
// EPI 1: out_f32 = acc + bias + res (fp32)
// EPI 2: out_bf16 = gelu_exact(acc + bias)
template<int EPI>
__global__ __launch_bounds__(256) void gemm128(
    const ushort* __restrict__ A, const ushort* __restrict__ BT,
    const float* __restrict__ bias, const float* __restrict__ res,
    float* __restrict__ outf, ushort* __restrict__ outb,
    ushort* __restrict__ oq, ushort* __restrict__ ok, ushort* __restrict__ ov,
    int N, int K){
  __shared__ short As[128][40];
  __shared__ short Bs[128][40];
  const int tid = threadIdx.x;
  const int mb = blockIdx.y, nb = blockIdx.x;
  const int wave = tid >> 6, lane = tid & 63;
  const int wm = wave >> 1, wn = wave & 1;
  const int lr = lane & 15, lg = lane >> 4;

  f32x4 acc[4][4] = {};

  const int ar = tid >> 2;            // 0..63
  const int ac = (tid & 3) * 8;       // 0,8,16,24
  const ushort* Abase = A  + (size_t)(mb * 128 + ar) * K + ac;
  const ushort* Bbase = BT + (size_t)(nb * 128 + ar) * K + ac;
  const int nK = K >> 5;

  for (int kt = 0; kt < nK; ++kt){
    const int ko = kt * 32;
    *reinterpret_cast<int4*>(&As[ar][ac])      = *reinterpret_cast<const int4*>(Abase + ko);
    *reinterpret_cast<int4*>(&As[ar + 64][ac]) = *reinterpret_cast<const int4*>(Abase + (size_t)64 * K + ko);
    *reinterpret_cast<int4*>(&Bs[ar][ac])      = *reinterpret_cast<const int4*>(Bbase + ko);
    *reinterpret_cast<int4*>(&Bs[ar + 64][ac]) = *reinterpret_cast<const int4*>(Bbase + (size_t)64 * K + ko);
    __syncthreads();
    bf16x8 af[4], bfr[4];
    #pragma unroll
    for (int mt = 0; mt < 4; mt++)
      af[mt] = *reinterpret_cast<const bf16x8*>(&As[wm * 64 + mt * 16 + lr][lg * 8]);
    #pragma unroll
    for (int nt = 0; nt < 4; nt++)
      bfr[nt] = *reinterpret_cast<const bf16x8*>(&Bs[wn * 64 + nt * 16 + lr][lg * 8]);
    #pragma unroll
    for (int mt = 0; mt < 4; mt++)
      #pragma unroll
      for (int nt = 0; nt < 4; nt++)
        acc[mt][nt] = __builtin_amdgcn_mfma_f32_16x16x32_bf16(af[mt], bfr[nt], acc[mt][nt], 0, 0, 0);
    __syncthreads();
  }

  #pragma unroll
  for (int mt = 0; mt < 4; mt++){
    #pragma unroll
    for (int nt = 0; nt < 4; nt++){
      #pragma unroll
      for (int r = 0; r < 4; r++){
        const int gm = mb * 128 + wm * 64 + mt * 16 + lg * 4 + r;
        const int gn = nb * 128 + wn * 64 + nt * 16 + lr;
        float val = acc[mt][nt][r] + bias[gn];
        if (EPI == 0){
          int p  = gn >> 10;
          int d  = gn & 1023;
          int h  = d >> 6, dh = d & 63;
          int bb = gm >> 11, s = gm & 2047;
          size_t idx = (((size_t)bb * Hc + h) * Sc + s) * DHc + dh;
          ushort* dst = (p == 0) ? oq : ((p == 1) ? ok : ov);
          dst[idx] = f2bf(val);
        } else if (EPI == 1){
          size_t i = (size_t)gm * N + gn;
          outf[i] = val + res[i];
        } else {
          float ge = 0.5f * val * (1.0f + erff(val * 0.70710678118f));
          outb[(size_t)gm * N + gn] = f2bf(ge);
        }
      }
    }
  }
}

// ---------------- Flash attention: q,k,v [B*H][S][DH] bf16 -> ctx [B,S,D] bf16 ----------------
__global__ __launch_bounds__(256) void flash_attn(const ushort* __restrict__ q,
                                                  const ushort* __restrict__ k,
                                                  const ushort* __restrict__ v,
                                                  ushort* __restrict__ ctx){
  const int bh = blockIdx.y;
  const int q0 = blockIdx.x * 64;
  const int b  = bh >> 4, h = bh & 15;
  const int tid = threadIdx.x, wave = tid >> 6, lane = tid & 63;
  const int lr = lane & 15, lg = lane >> 4;

  __shared__ short Ks[64][72];
  __shared__ short Vt[64][72];   // [dh][key]
  __shared__ short Ps[4][16][72];

  const ushort* qb = q + (size_t)bh * Sc * DHc;
  const ushort* kb = k + (size_t)bh * Sc * DHc;
  const ushort* vb = v + (size_t)bh * Sc * DHc;

  bf16x8 qf[2];
  {
    const ushort* qp = qb + (size_t)(q0 + wave * 16 + lr) * DHc + lg * 8;
    qf[0] = *reinterpret_cast<const bf16x8*>(qp);
    qf[1] = *reinterpret_cast<const bf16x8*>(qp + 32);
  }

  float mrow[4], lrow[4];
  #pragma unroll
  for (int j = 0; j < 4; j++){ mrow[j] = -INFINITY; lrow[j] = 0.f; }
  f32x4 o[4] = {};
  const float scale = 0.125f;

  for (int kt = 0; kt < Sc / 64; ++kt){
    __syncthreads();
    {
      int r = tid >> 2; int c = (tid & 3) * 16;
      const ushort* kg = kb + (size_t)(kt * 64 + r) * DHc + c;
      *reinterpret_cast<int4*>(&Ks[r][c])     = *reinterpret_cast<const int4*>(kg);
      *reinterpret_cast<int4*>(&Ks[r][c + 8]) = *reinterpret_cast<const int4*>(kg + 8);
      int vr = tid >> 3; int vc = (tid & 7) * 8;
      #pragma unroll
      for (int it = 0; it < 2; ++it){
        int rr = vr + it * 32;
        ushort tmp[8];
        *reinterpret_cast<int4*>(tmp) =
            *reinterpret_cast<const int4*>(vb + (size_t)(kt * 64 + rr) * DHc + vc);
        #pragma unroll
        for (int i = 0; i < 8; i++) Vt[vc + i][rr] = tmp[i];
      }
    }
    __syncthreads();

    // S = Q @ K^T * scale   (rows: lg*4+j owned per lane group; cols: nt*16+lr)
    f32x4 sacc[4];
    #pragma unroll
    for (int nt = 0; nt < 4; nt++){
      bf16x8 b0 = *reinterpret_cast<const bf16x8*>(&Ks[nt * 16 + lr][lg * 8]);
      bf16x8 b1 = *reinterpret_cast<const bf16x8*>(&Ks[nt * 16 + lr][32 + lg * 8]);
      f32x4 z = {0.f, 0.f, 0.f, 0.f};
      z = __builtin_amdgcn_mfma_f32_16x16x32_bf16(qf[0], b0, z, 0, 0, 0);
      z = __builtin_amdgcn_mfma_f32_16x16x32_bf16(qf[1], b1, z, 0, 0, 0);
      sacc[nt] = z;
    }
    float cm[4];
    #pragma unroll
    for (int j = 0; j < 4; j++){
      float a0 = sacc[0][j] * scale, a1 = sacc[1][j] * scale;
      float a2 = sacc[2][j] * scale, a3 = sacc[3][j] * scale;
      sacc[0][j] = a0; sacc[1][j] = a1; sacc[2][j] = a2; sacc[3][j] = a3;
      cm[j] = fmaxf(fmaxf(a0, a1), fmaxf(a2, a3));
    }
    #pragma unroll
    for (int m = 1; m < 16; m <<= 1)
      #pragma unroll
      for (int j = 0; j < 4; j++) cm[j] = fmaxf(cm[j], __shfl_xor(cm[j], m));
    float fac[4];
    #pragma unroll
    for (int j = 0; j < 4; j++){
      float mn = fmaxf(mrow[j], cm[j]);
      fac[j] = expf(mrow[j] - mn);
      mrow[j] = mn;
    }
    float rs[4];
    #pragma unroll
    for (int j = 0; j < 4; j++){
      float p0 = expf(sacc[0][j] - mrow[j]);
      float p1 = expf(sacc[1][j] - mrow[j]);
      float p2 = expf(sacc[2][j] - mrow[j]);
      float p3 = expf(sacc[3][j] - mrow[j]);
      sacc[0][j] = p0; sacc[1][j] = p1; sacc[2][j] = p2; sacc[3][j] = p3;
      rs[j] = p0 + p1 + p2 + p3;
    }
    #pragma unroll
    for (int m = 1; m < 16; m <<= 1)
      #pragma unroll
      for (int j = 0; j < 4; j++) rs[j] += __shfl_xor(rs[j], m);
    #pragma unroll
    for (int j = 0; j < 4; j++) lrow[j] = lrow[j] * fac[j] + rs[j];
    #pragma unroll
    for (int nt = 0; nt < 4; nt++)
      #pragma unroll
      for (int j = 0; j < 4; j++) o[nt][j] *= fac[j];
    #pragma unroll
    for (int nt = 0; nt < 4; nt++)
      #pragma unroll
      for (int j = 0; j < 4; j++)
        Ps[wave][lg * 4 + j][nt * 16 + lr] = (short)f2bf(sacc[nt][j]);
    __syncthreads();

    bf16x8 pf0 = *reinterpret_cast<const bf16x8*>(&Ps[wave][lr][lg * 8]);
    bf16x8 pf1 = *reinterpret_cast<const bf16x8*>(&Ps[wave][lr][32 + lg * 8]);
    #pragma unroll
    for (int nt = 0; nt < 4; nt++){
      bf16x8 v0 = *reinterpret_cast<const bf16x8*>(&Vt[nt * 16 + lr][lg * 8]);
      bf16x8 v1 = *reinterpret_cast<const bf16x8*>(&Vt[nt * 16 + lr][32 + lg * 8]);
      o[nt] = __builtin_amdgcn_mfma_f32_16x16x32_bf16(pf0, v0, o[nt], 0, 0, 0);
      o[nt] = __builtin_amdgcn_mfma_f32_16x16x32_bf16(pf1, v1, o[nt], 0, 0, 0);
    }
  }

  #pragma unroll
  for (int j = 0; j < 4; j++){
    float inv = 1.0f / lrow[j];
    int s = q0 + wave * 16 + lg * 4 + j;
    ushort* op = ctx + ((size_t)b * Sc + s) * Dc + h * DHc;
    #pragma unroll
    for (int nt = 0; nt < 4; nt++)
      op[nt * 16 + lr] = f2bf(o[nt][j] * inv);
  }
}

// ---------------- orchestration ----------------
extern "C" void kernel_launch(void* const* d_in, const int* in_sizes, int n_in,
                              void* d_out, int out_size, void* d_ws, size_t ws_size,
                              hipStream_t stream){
  const float* x     = (const float*)d_in[0];
  const float* ln1_g = (const float*)d_in[1];
  const float* ln1_b = (const float*)d_in[2];
  const float* w_qkv = (const float*)d_in[3];
  const float* b_qkv = (const float*)d_in[4];
  const float* w_out = (const float*)d_in[5];
  const float* b_out = (const float*)d_in[6];
  const float* ln2_g = (const float*)d_in[7];
  const float* ln2_b = (const float*)d_in[8];
  const float* w1    = (const float*)d_in[9];
  const float* b1    = (const float*)d_in[10];
  const float* w2    = (const float*)d_in[11];
  const float* b2    = (const float*)d_in[12];
  float* out = (float*)d_out;

  char* ws = (char*)d_ws;
  size_t off = 0;
  ushort* wqkvT = (ushort*)(ws + off); off += (size_t)3072 * 1024 * 2;
  ushort* woutT = (ushort*)(ws + off); off += (size_t)1024 * 1024 * 2;
  ushort* w1T   = (ushort*)(ws + off); off += (size_t)4096 * 1024 * 2;
  ushort* w2T   = (ushort*)(ws + off); off += (size_t)1024 * 4096 * 2;
  ushort* hln   = (ushort*)(ws + off); off += (size_t)Mc * Dc * 2;
  ushort* qbuf  = (ushort*)(ws + off); off += (size_t)32 * Sc * DHc * 2;
  ushort* kbuf  = (ushort*)(ws + off); off += (size_t)32 * Sc * DHc * 2;
  ushort* vbuf  = (ushort*)(ws + off); off += (size_t)32 * Sc * DHc * 2;
  ushort* ctx   = (ushort*)(ws + off); off += (size_t)Mc * Dc * 2;
  float*  x1    = (float*)(ws + off);  off += (size_t)Mc * Dc * 4;
  ushort* act   = qbuf;  // reuse q/k/v + ctx region (33.5 MB), dead after attn+out-proj

  // 1. weight transpose+cast
  tcast<<<dim3(3072 / 32, 1024 / 32), 256, 0, stream>>>(w_qkv, wqkvT, 1024, 3072);
  tcast<<<dim3(1024 / 32, 1024 / 32), 256, 0, stream>>>(w_out, woutT, 1024, 1024);
  tcast<<<dim3(4096 / 32, 1024 / 32), 256, 0, stream>>>(w1,    w1T,   1024, 4096);
  tcast<<<dim3(1024 / 32, 4096 / 32), 256, 0, stream>>>(w2,    w2T,   4096, 1024);

  // 2. LN1
  ln_bf16<<<Mc, 256, 0, stream>>>(x, ln1_g, ln1_b, hln);

  // 3. QKV projection + head scatter
  gemm128<0><<<dim3(3072 / 128, Mc / 128), 256, 0, stream>>>(
      hln, wqkvT, b_qkv, nullptr, nullptr, nullptr, qbuf, kbuf, vbuf, 3072, 1024);

  // 4. attention
  flash_attn<<<dim3(Sc / 64, 32), 256, 0, stream>>>(qbuf, kbuf, vbuf, ctx);

  // 5. out proj + residual -> x1
  gemm128<1><<<dim3(1024 / 128, Mc / 128), 256, 0, stream>>>(
      ctx, woutT, b_out, x, x1, nullptr, nullptr, nullptr, nullptr, 1024, 1024);

  // 6. LN2
  ln_bf16<<<Mc, 256, 0, stream>>>(x1, ln2_g, ln2_b, hln);

  // 7. MLP up + GELU
  gemm128<2><<<dim3(4096 / 128, Mc / 128), 256, 0, stream>>>(
      hln, w1T, b1, nullptr, nullptr, act, nullptr, nullptr, nullptr, 4096, 1024);

  // 8. MLP down + residual -> out
  gemm128<1><<<dim3(1024 / 128, Mc / 128), 256, 0, stream>>>(
      act, w2T, b2, x1, out, nullptr, nullptr, nullptr, nullptr, 1024, 4096);
}

// Round 2
// 384.397 us; speedup vs baseline: 1.1970x; 1.1970x over previous
//
#include <hip/hip_runtime.h>
#include <hip/hip_bf16.h>
#include <math.h>

#define Bc 2
#define Sc 2048
#define Dc 1024
#define Hc 16
#define DHc 64
#define Mc (Bc*Sc)   // 4096

typedef __attribute__((ext_vector_type(8))) short bf16x8;
typedef __attribute__((ext_vector_type(4))) float f32x4;

__device__ __forceinline__ ushort f2bf(float f){
  union { float f; uint32_t u; } c; c.f = f;
  uint32_t u = c.u;
  return (ushort)((u + 0x7fffu + ((u >> 16) & 1u)) >> 16);
}

// async global -> LDS, 16B per lane. lbase must be wave-uniform; HW adds lane*16.
__device__ __forceinline__ void stage16(const void* g, void* lbase, int lane){
#if __has_builtin(__builtin_amdgcn_global_load_lds)
  __builtin_amdgcn_global_load_lds(
      (const __attribute__((address_space(1))) void*)g,
      (__attribute__((address_space(3))) void*)lbase, 16, 0, 0);
#else
  *(int4*)((char*)lbase + lane*16) = *(const int4*)g;
#endif
}

// ---------------- transpose + cast: w[K][N] f32 -> wT[N][K] bf16 ----------------
__global__ __launch_bounds__(256) void tcast(const float* __restrict__ w,
                                             ushort* __restrict__ wt,
                                             int K, int N){
  __shared__ float t[32][33];
  int kb = blockIdx.y * 32, nb = blockIdx.x * 32;
  int tx = threadIdx.x & 31, ty = threadIdx.x >> 5;
  #pragma unroll
  for (int i = 0; i < 4; i++)
    t[ty + 8*i][tx] = w[(size_t)(kb + ty + 8*i) * N + nb + tx];
  __syncthreads();
  #pragma unroll
  for (int i = 0; i < 4; i++)
    wt[(size_t)(nb + ty + 8*i) * K + kb + tx] = f2bf(t[tx][ty + 8*i]);
}

// ---------------- LayerNorm -> bf16 ----------------
__global__ __launch_bounds__(256) void ln_bf16(const float* __restrict__ x,
                                               const float* __restrict__ g,
                                               const float* __restrict__ b,
                                               ushort* __restrict__ out){
  int row = blockIdx.x;
  const float4 xv = reinterpret_cast<const float4*>(x + (size_t)row * Dc)[threadIdx.x];
  float s  = xv.x + xv.y + xv.z + xv.w;
  float sq = xv.x*xv.x + xv.y*xv.y + xv.z*xv.z + xv.w*xv.w;
  #pragma unroll
  for (int m = 1; m < 64; m <<= 1){ s += __shfl_xor(s, m); sq += __shfl_xor(sq, m); }
  __shared__ float ss[4], ssq[4];
  int wv = threadIdx.x >> 6;
  if ((threadIdx.x & 63) == 0){ ss[wv] = s; ssq[wv] = sq; }
  __syncthreads();
  s  = ss[0] + ss[1] + ss[2] + ss[3];
  sq = ssq[0] + ssq[1] + ssq[2] + ssq[3];
  float mu  = s * (1.0f / Dc);
  float var = sq * (1.0f / Dc) - mu * mu;
  float rstd = rsqrtf(var + 1e-5f);
  float4 gv = reinterpret_cast<const float4*>(g)[threadIdx.x];
  float4 bv = reinterpret_cast<const float4*>(b)[threadIdx.x];
  ushort o[4];
  o[0] = f2bf((xv.x - mu) * rstd * gv.x + bv.x);
  o[1] = f2bf((xv.y - mu) * rstd * gv.y + bv.y);
  o[2] = f2bf((xv.z - mu) * rstd * gv.z + bv.z);
  o[3] = f2bf((xv.w - mu) * rstd * gv.w + bv.w);
  *reinterpret_cast<uint2*>(out + (size_t)row * Dc + threadIdx.x * 4) =
      *reinterpret_cast<uint2*>(o);
}

// ---------------- GEMM: C[M,N] = A[M,K](bf16) @ BT[N,K]^T(bf16) + bias ----------------
// EPI 0: qkv scatter -> q/k [B*H][S][DH] bf16, v -> vt [B*H][DH][S] bf16 (pre-transposed)
// EPI 1: out_f32 = acc + bias + res (fp32)
// EPI 2: out_bf16 = gelu_exact(acc + bias)
template<int EPI>
__global__ __launch_bounds__(256) void gemm128(
    const ushort* __restrict__ A, const ushort* __restrict__ BT,
    const float* __restrict__ bias, const float* __restrict__ res,
    float* __restrict__ outf, ushort* __restrict__ outb,
    ushort* __restrict__ oq, ushort* __restrict__ ok, ushort* __restrict__ ov,
    int N, int K){
  __shared__ short As[128*32];   // [row][32 shorts], 64B rows, linear for global_load_lds
  __shared__ short Bs[128*32];
  const int tid = threadIdx.x;
  const int mb = blockIdx.y, nb = blockIdx.x;
  const int wave = tid >> 6, lane = tid & 63;
  const int wm = wave >> 1, wn = wave & 1;
  const int lr = lane & 15, lg = lane >> 4;

  f32x4 acc[4][4] = {};

  const int sr = tid >> 2;          // staging row 0..63
  const int sc = (tid & 3) * 8;     // staging col (shorts)
  const ushort* Ag = A  + (size_t)(mb * 128 + sr) * K + sc;
  const ushort* Bg = BT + (size_t)(nb * 128 + sr) * K + sc;
  char* Asw = (char*)As + wave * 1024;
  char* Bsw = (char*)Bs + wave * 1024;
  const int nK = K >> 5;

  for (int kt = 0; kt < nK; ++kt){
    const int ko = kt * 32;
    stage16(Ag + ko,                 Asw,        lane);
    stage16(Ag + (size_t)64*K + ko,  Asw + 4096, lane);
    stage16(Bg + ko,                 Bsw,        lane);
    stage16(Bg + (size_t)64*K + ko,  Bsw + 4096, lane);
    __syncthreads();
    bf16x8 af[4], bfr[4];
    #pragma unroll
    for (int mt = 0; mt < 4; mt++)
      af[mt] = *reinterpret_cast<const bf16x8*>(&As[(wm*64 + mt*16 + lr)*32 + lg*8]);
    #pragma unroll
    for (int nt = 0; nt < 4; nt++)
      bfr[nt] = *reinterpret_cast<const bf16x8*>(&Bs[(wn*64 + nt*16 + lr)*32 + lg*8]);
    #pragma unroll
    for (int mt = 0; mt < 4; mt++)
      #pragma unroll
      for (int nt = 0; nt < 4; nt++)
        acc[mt][nt] = __builtin_amdgcn_mfma_f32_16x16x32_bf16(af[mt], bfr[nt], acc[mt][nt], 0, 0, 0);
    __syncthreads();
  }

  if (EPI == 0){
    #pragma unroll
    for (int mt = 0; mt < 4; mt++){
      const int gm0 = mb * 128 + wm * 64 + mt * 16 + lg * 4;
      const int bb = gm0 >> 11, s0 = gm0 & 2047;
      #pragma unroll
      for (int nt = 0; nt < 4; nt++){
        const int gn = nb * 128 + wn * 64 + nt * 16 + lr;
        const float bv = bias[gn];
        const int p = gn >> 10, d = gn & 1023;
        const int hh = d >> 6, dh = d & 63;
        const int bh = bb * Hc + hh;
        if (p == 2){
          ushort pk[4];
          #pragma unroll
          for (int r = 0; r < 4; r++) pk[r] = f2bf(acc[mt][nt][r] + bv);
          *reinterpret_cast<uint2*>(ov + ((size_t)bh * DHc + dh) * Sc + s0) =
              *reinterpret_cast<uint2*>(pk);
        } else {
          ushort* dst = (p == 0) ? oq : ok;
          #pragma unroll
          for (int r = 0; r < 4; r++)
            dst[((size_t)bh * Sc + s0 + r) * DHc + dh] = f2bf(acc[mt][nt][r] + bv);
        }
      }
    }
  } else {
    #pragma unroll
    for (int mt = 0; mt < 4; mt++){
      #pragma unroll
      for (int nt = 0; nt < 4; nt++){
        #pragma unroll
        for (int r = 0; r < 4; r++){
          const int gm = mb * 128 + wm * 64 + mt * 16 + lg * 4 + r;
          const int gn = nb * 128 + wn * 64 + nt * 16 + lr;
          float val = acc[mt][nt][r] + bias[gn];
          if (EPI == 1){
            size_t i = (size_t)gm * N + gn;
            outf[i] = val + res[i];
          } else {
            float ge = 0.5f * val * (1.0f + erff(val * 0.70710678118f));
            outb[(size_t)gm * N + gn] = f2bf(ge);
          }
        }
      }
    }
  }
}

// ---------------- Flash attention ----------------
// q,k: [B*H][S][DH] bf16; vt: [B*H][DH][S] bf16 (pre-transposed); ctx: [B,S,D] bf16
__global__ __launch_bounds__(256) void flash_attn(const ushort* __restrict__ q,
                                                  const ushort* __restrict__ k,
                                                  const ushort* __restrict__ vt,
                                                  ushort* __restrict__ ctx){
  const int bh = blockIdx.y;
  const int q0 = blockIdx.x * 64;
  const int b  = bh >> 4, h = bh & 15;
  const int tid = threadIdx.x, wave = tid >> 6, lane = tid & 63;
  const int lr = lane & 15, lg = lane >> 4;

  // linear 64-row x 64B tiles -> global_load_lds friendly, conflict-free b128 reads
  __shared__ short Klo[64*32];   // K rows, dh 0..31
  __shared__ short Khi[64*32];   // K rows, dh 32..63
  __shared__ short Vlo[64*32];   // V^T rows (dh), kv 0..31
  __shared__ short Vhi[64*32];   // V^T rows (dh), kv 32..63
  __shared__ short Ps[4][16][72];

  const ushort* qb = q + (size_t)bh * Sc * DHc;
  const int sr = tid >> 2, sc = (tid & 3) * 8;
  const ushort* kg = k  + (size_t)bh * Sc * DHc + (size_t)sr * DHc + sc;
  const ushort* vg = vt + (size_t)bh * DHc * Sc + (size_t)sr * Sc  + sc;
  char* Klw = (char*)Klo + wave * 1024;
  char* Khw = (char*)Khi + wave * 1024;
  char* Vlw = (char*)Vlo + wave * 1024;
  char* Vhw = (char*)Vhi + wave * 1024;

  bf16x8 qf0, qf1;
  {
    const ushort* qp = qb + (size_t)(q0 + wave * 16 + lr) * DHc + lg * 8;
    qf0 = *reinterpret_cast<const bf16x8*>(qp);
    qf1 = *reinterpret_cast<const bf16x8*>(qp + 32);
  }

  float mrow[4], lrow[4];
  #pragma unroll
  for (int j = 0; j < 4; j++){ mrow[j] = -INFINITY; lrow[j] = 0.f; }
  f32x4 o[4] = {};
  const float cexp = 0.18033688f;   // dh^-0.5 * log2(e) = 0.125 * 1.4426950

  for (int kt = 0; kt < Sc / 64; ++kt){
    __syncthreads();   // all waves done reading previous tile
    stage16(kg + (size_t)kt * 64 * DHc,      Klw, lane);
    stage16(kg + (size_t)kt * 64 * DHc + 32, Khw, lane);
    stage16(vg + kt * 64,                    Vlw, lane);
    stage16(vg + kt * 64 + 32,               Vhw, lane);
    __syncthreads();   // drains vmcnt -> tiles visible

    // raw scores S = Q K^T (scale folded into exp2 domain)
    f32x4 sacc[4];
    #pragma unroll
    for (int nt = 0; nt < 4; nt++){
      bf16x8 b0 = *reinterpret_cast<const bf16x8*>(&Klo[(nt*16 + lr)*32 + lg*8]);
      bf16x8 b1 = *reinterpret_cast<const bf16x8*>(&Khi[(nt*16 + lr)*32 + lg*8]);
      f32x4 z = {0.f, 0.f, 0.f, 0.f};
      z = __builtin_amdgcn_mfma_f32_16x16x32_bf16(qf0, b0, z, 0, 0, 0);
      z = __builtin_amdgcn_mfma_f32_16x16x32_bf16(qf1, b1, z, 0, 0, 0);
      sacc[nt] = z;
    }
    float cm[4];
    #pragma unroll
    for (int j = 0; j < 4; j++)
      cm[j] = fmaxf(fmaxf(sacc[0][j], sacc[1][j]), fmaxf(sacc[2][j], sacc[3][j]));
    #pragma unroll
    for (int m = 1; m < 16; m <<= 1)
      #pragma unroll
      for (int j = 0; j < 4; j++) cm[j] = fmaxf(cm[j], __shfl_xor(cm[j], m));
    float fac[4];
    #pragma unroll
    for (int j = 0; j < 4; j++){
      float mn = fmaxf(mrow[j], cm[j]);
      fac[j] = exp2f((mrow[j] - mn) * cexp);
      mrow[j] = mn;
    }
    float rs[4];
    #pragma unroll
    for (int j = 0; j < 4; j++){
      float p0 = exp2f((sacc[0][j] - mrow[j]) * cexp);
      float p1 = exp2f((sacc[1][j] - mrow[j]) * cexp);
      float p2 = exp2f((sacc[2][j] - mrow[j]) * cexp);
      float p3 = exp2f((sacc[3][j] - mrow[j]) * cexp);
      sacc[0][j] = p0; sacc[1][j] = p1; sacc[2][j] = p2; sacc[3][j] = p3;
      rs[j] = p0 + p1 + p2 + p3;
    }
    #pragma unroll
    for (int m = 1; m < 16; m <<= 1)
      #pragma unroll
      for (int j = 0; j < 4; j++) rs[j] += __shfl_xor(rs[j], m);
    #pragma unroll
    for (int j = 0; j < 4; j++) lrow[j] = lrow[j] * fac[j] + rs[j];
    #pragma unroll
    for (int nt = 0; nt < 4; nt++)
      #pragma unroll
      for (int j = 0; j < 4; j++) o[nt][j] *= fac[j];
    // P -> LDS (per-wave slice; no barrier needed, lgkmcnt orders within wave)
    #pragma unroll
    for (int nt = 0; nt < 4; nt++)
      #pragma unroll
      for (int j = 0; j < 4; j++)
        Ps[wave][lg * 4 + j][nt * 16 + lr] = (short)f2bf(sacc[nt][j]);

    bf16x8 pf0 = *reinterpret_cast<const bf16x8*>(&Ps[wave][lr][lg * 8]);
    bf16x8 pf1 = *reinterpret_cast<const bf16x8*>(&Ps[wave][lr][32 + lg * 8]);
    #pragma unroll
    for (int nt = 0; nt < 4; nt++){
      bf16x8 v0 = *reinterpret_cast<const bf16x8*>(&Vlo[(nt*16 + lr)*32 + lg*8]);
      bf16x8 v1 = *reinterpret_cast<const bf16x8*>(&Vhi[(nt*16 + lr)*32 + lg*8]);
      o[nt] = __builtin_amdgcn_mfma_f32_16x16x32_bf16(pf0, v0, o[nt], 0, 0, 0);
      o[nt] = __builtin_amdgcn_mfma_f32_16x16x32_bf16(pf1, v1, o[nt], 0, 0, 0);
    }
  }

  #pragma unroll
  for (int j = 0; j < 4; j++){
    float inv = 1.0f / lrow[j];
    int s = q0 + wave * 16 + lg * 4 + j;
    ushort* op = ctx + ((size_t)b * Sc + s) * Dc + h * DHc;
    #pragma unroll
    for (int nt = 0; nt < 4; nt++)
      op[nt * 16 + lr] = f2bf(o[nt][j] * inv);
  }
}

// ---------------- orchestration ----------------
extern "C" void kernel_launch(void* const* d_in, const int* in_sizes, int n_in,
                              void* d_out, int out_size, void* d_ws, size_t ws_size,
                              hipStream_t stream){
  const float* x     = (const float*)d_in[0];
  const float* ln1_g = (const float*)d_in[1];
  const float* ln1_b = (const float*)d_in[2];
  const float* w_qkv = (const float*)d_in[3];
  const float* b_qkv = (const float*)d_in[4];
  const float* w_out = (const float*)d_in[5];
  const float* b_out = (const float*)d_in[6];
  const float* ln2_g = (const float*)d_in[7];
  const float* ln2_b = (const float*)d_in[8];
  const float* w1    = (const float*)d_in[9];
  const float* b1    = (const float*)d_in[10];
  const float* w2    = (const float*)d_in[11];
  const float* b2    = (const float*)d_in[12];
  float* out = (float*)d_out;

  char* ws = (char*)d_ws;
  size_t off = 0;
  ushort* wqkvT = (ushort*)(ws + off); off += (size_t)3072 * 1024 * 2;
  ushort* woutT = (ushort*)(ws + off); off += (size_t)1024 * 1024 * 2;
  ushort* w1T   = (ushort*)(ws + off); off += (size_t)4096 * 1024 * 2;
  ushort* w2T   = (ushort*)(ws + off); off += (size_t)1024 * 4096 * 2;
  ushort* hln   = (ushort*)(ws + off); off += (size_t)Mc * Dc * 2;
  ushort* qbuf  = (ushort*)(ws + off); off += (size_t)32 * Sc * DHc * 2;
  ushort* kbuf  = (ushort*)(ws + off); off += (size_t)32 * Sc * DHc * 2;
  ushort* vtbuf = (ushort*)(ws + off); off += (size_t)32 * Sc * DHc * 2;
  ushort* ctx   = (ushort*)(ws + off); off += (size_t)Mc * Dc * 2;
  float*  x1    = (float*)(ws + off);  off += (size_t)Mc * Dc * 4;
  ushort* act   = qbuf;  // reuse q/k/vt + ctx region (32 MB), dead after out-proj

  // 1. weight transpose+cast
  tcast<<<dim3(3072 / 32, 1024 / 32), 256, 0, stream>>>(w_qkv, wqkvT, 1024, 3072);
  tcast<<<dim3(1024 / 32, 1024 / 32), 256, 0, stream>>>(w_out, woutT, 1024, 1024);
  tcast<<<dim3(4096 / 32, 1024 / 32), 256, 0, stream>>>(w1,    w1T,   1024, 4096);
  tcast<<<dim3(1024 / 32, 4096 / 32), 256, 0, stream>>>(w2,    w2T,   4096, 1024);

  // 2. LN1
  ln_bf16<<<Mc, 256, 0, stream>>>(x, ln1_g, ln1_b, hln);

  // 3. QKV projection + head scatter (v pre-transposed)
  gemm128<0><<<dim3(3072 / 128, Mc / 128), 256, 0, stream>>>(
      hln, wqkvT, b_qkv, nullptr, nullptr, nullptr, qbuf, kbuf, vtbuf, 3072, 1024);

  // 4. attention
  flash_attn<<<dim3(Sc / 64, 32), 256, 0, stream>>>(qbuf, kbuf, vtbuf, ctx);

  // 5. out proj + residual -> x1
  gemm128<1><<<dim3(1024 / 128, Mc / 128), 256, 0, stream>>>(
      ctx, woutT, b_out, x, x1, nullptr, nullptr, nullptr, nullptr, 1024, 1024);

  // 6. LN2
  ln_bf16<<<Mc, 256, 0, stream>>>(x1, ln2_g, ln2_b, hln);

  // 7. MLP up + GELU
  gemm128<2><<<dim3(4096 / 128, Mc / 128), 256, 0, stream>>>(
      hln, w1T, b1, nullptr, nullptr, act, nullptr, nullptr, nullptr, 4096, 1024);

  // 8. MLP down + residual -> out
  gemm128<1><<<dim3(1024 / 128, Mc / 128), 256, 0, stream>>>(
      act, w2T, b2, x1, out, nullptr, nullptr, nullptr, nullptr, 1024, 4096);
}

// Round 3
// 347.971 us; speedup vs baseline: 1.3223x; 1.1047x over previous
//
#include <hip/hip_runtime.h>
#include <hip/hip_bf16.h>
#include <math.h>

#define Bc 2
#define Sc 2048
#define Dc 1024
#define Hc 16
#define DHc 64
#define Mc (Bc*Sc)   // 4096

typedef __attribute__((ext_vector_type(8))) short bf16x8;
typedef __attribute__((ext_vector_type(4))) float f32x4;

// dh^-0.5 * log2(e), folded into Q at the QKV epilogue
#define QSCALE 0.18033688f

__device__ __forceinline__ ushort f2bf(float f){
  union { float f; uint32_t u; } c; c.f = f;
  uint32_t u = c.u;
  return (ushort)((u + 0x7fffu + ((u >> 16) & 1u)) >> 16);
}
// cheap round-half-up bf16 pack (for P in [0, 2^16]); 2 VALU ops
__device__ __forceinline__ ushort f2bf_fast(float f){
  union { float f; uint32_t u; } c; c.f = f;
  return (ushort)((c.u + 0x8000u) >> 16);
}

// async global -> LDS, 16B per lane. lbase must be wave-uniform; HW adds lane*16.
__device__ __forceinline__ void stage16(const void* g, void* lbase, int lane){
#if __has_builtin(__builtin_amdgcn_global_load_lds)
  __builtin_amdgcn_global_load_lds(
      (const __attribute__((address_space(1))) void*)g,
      (__attribute__((address_space(3))) void*)lbase, 16, 0, 0);
#else
  *(int4*)((char*)lbase + lane*16) = *(const int4*)g;
#endif
}

// ---------------- transpose + cast: w[K][N] f32 -> wT[N][K] bf16 ----------------
__global__ __launch_bounds__(256) void tcast(const float* __restrict__ w,
                                             ushort* __restrict__ wt,
                                             int K, int N){
  __shared__ float t[32][33];
  int kb = blockIdx.y * 32, nb = blockIdx.x * 32;
  int tx = threadIdx.x & 31, ty = threadIdx.x >> 5;
  #pragma unroll
  for (int i = 0; i < 4; i++)
    t[ty + 8*i][tx] = w[(size_t)(kb + ty + 8*i) * N + nb + tx];
  __syncthreads();
  #pragma unroll
  for (int i = 0; i < 4; i++)
    wt[(size_t)(nb + ty + 8*i) * K + kb + tx] = f2bf(t[tx][ty + 8*i]);
}

// ---------------- LayerNorm -> bf16 ----------------
__global__ __launch_bounds__(256) void ln_bf16(const float* __restrict__ x,
                                               const float* __restrict__ g,
                                               const float* __restrict__ b,
                                               ushort* __restrict__ out){
  int row = blockIdx.x;
  const float4 xv = reinterpret_cast<const float4*>(x + (size_t)row * Dc)[threadIdx.x];
  float s  = xv.x + xv.y + xv.z + xv.w;
  float sq = xv.x*xv.x + xv.y*xv.y + xv.z*xv.z + xv.w*xv.w;
  #pragma unroll
  for (int m = 1; m < 64; m <<= 1){ s += __shfl_xor(s, m); sq += __shfl_xor(sq, m); }
  __shared__ float ss[4], ssq[4];
  int wv = threadIdx.x >> 6;
  if ((threadIdx.x & 63) == 0){ ss[wv] = s; ssq[wv] = sq; }
  __syncthreads();
  s  = ss[0] + ss[1] + ss[2] + ss[3];
  sq = ssq[0] + ssq[1] + ssq[2] + ssq[3];
  float mu  = s * (1.0f / Dc);
  float var = sq * (1.0f / Dc) - mu * mu;
  float rstd = rsqrtf(var + 1e-5f);
  float4 gv = reinterpret_cast<const float4*>(g)[threadIdx.x];
  float4 bv = reinterpret_cast<const float4*>(b)[threadIdx.x];
  ushort o[4];
  o[0] = f2bf((xv.x - mu) * rstd * gv.x + bv.x);
  o[1] = f2bf((xv.y - mu) * rstd * gv.y + bv.y);
  o[2] = f2bf((xv.z - mu) * rstd * gv.z + bv.z);
  o[3] = f2bf((xv.w - mu) * rstd * gv.w + bv.w);
  *reinterpret_cast<uint2*>(out + (size_t)row * Dc + threadIdx.x * 4) =
      *reinterpret_cast<uint2*>(o);
}

// ---------------- GEMM: C[M,N] = A[M,K](bf16) @ BT[N,K]^T(bf16) + bias ----------------
// EPI 0: qkv scatter -> q (pre-scaled by QSCALE) / k [B*H][S][DH] bf16,
//        v -> vt [B*H][DH][S] bf16 (pre-transposed)
// EPI 1: out_f32 = acc + bias + res (fp32)
// EPI 2: out_bf16 = gelu_exact(acc + bias)
template<int EPI>
__global__ __launch_bounds__(256) void gemm128(
    const ushort* __restrict__ A, const ushort* __restrict__ BT,
    const float* __restrict__ bias, const float* __restrict__ res,
    float* __restrict__ outf, ushort* __restrict__ outb,
    ushort* __restrict__ oq, ushort* __restrict__ ok, ushort* __restrict__ ov,
    int N, int K){
  __shared__ short As[128*32];   // [row][32 shorts], 64B rows, linear for global_load_lds
  __shared__ short Bs[128*32];
  const int tid = threadIdx.x;
  const int mb = blockIdx.y, nb = blockIdx.x;
  const int wave = tid >> 6, lane = tid & 63;
  const int wm = wave >> 1, wn = wave & 1;
  const int lr = lane & 15, lg = lane >> 4;

  f32x4 acc[4][4] = {};

  const int sr = tid >> 2;          // staging row 0..63
  const int sc = (tid & 3) * 8;     // staging col (shorts)
  const ushort* Ag = A  + (size_t)(mb * 128 + sr) * K + sc;
  const ushort* Bg = BT + (size_t)(nb * 128 + sr) * K + sc;
  char* Asw = (char*)As + wave * 1024;
  char* Bsw = (char*)Bs + wave * 1024;
  const int nK = K >> 5;

  for (int kt = 0; kt < nK; ++kt){
    const int ko = kt * 32;
    stage16(Ag + ko,                 Asw,        lane);
    stage16(Ag + (size_t)64*K + ko,  Asw + 4096, lane);
    stage16(Bg + ko,                 Bsw,        lane);
    stage16(Bg + (size_t)64*K + ko,  Bsw + 4096, lane);
    __syncthreads();
    bf16x8 af[4], bfr[4];
    #pragma unroll
    for (int mt = 0; mt < 4; mt++)
      af[mt] = *reinterpret_cast<const bf16x8*>(&As[(wm*64 + mt*16 + lr)*32 + lg*8]);
    #pragma unroll
    for (int nt = 0; nt < 4; nt++)
      bfr[nt] = *reinterpret_cast<const bf16x8*>(&Bs[(wn*64 + nt*16 + lr)*32 + lg*8]);
    #pragma unroll
    for (int mt = 0; mt < 4; mt++)
      #pragma unroll
      for (int nt = 0; nt < 4; nt++)
        acc[mt][nt] = __builtin_amdgcn_mfma_f32_16x16x32_bf16(af[mt], bfr[nt], acc[mt][nt], 0, 0, 0);
    __syncthreads();
  }

  if (EPI == 0){
    #pragma unroll
    for (int mt = 0; mt < 4; mt++){
      const int gm0 = mb * 128 + wm * 64 + mt * 16 + lg * 4;
      const int bb = gm0 >> 11, s0 = gm0 & 2047;
      #pragma unroll
      for (int nt = 0; nt < 4; nt++){
        const int gn = nb * 128 + wn * 64 + nt * 16 + lr;
        const float bv = bias[gn];
        const int p = gn >> 10, d = gn & 1023;
        const int hh = d >> 6, dh = d & 63;
        const int bh = bb * Hc + hh;
        if (p == 2){
          ushort pk[4];
          #pragma unroll
          for (int r = 0; r < 4; r++) pk[r] = f2bf(acc[mt][nt][r] + bv);
          *reinterpret_cast<uint2*>(ov + ((size_t)bh * DHc + dh) * Sc + s0) =
              *reinterpret_cast<uint2*>(pk);
        } else if (p == 0){
          #pragma unroll
          for (int r = 0; r < 4; r++)
            oq[((size_t)bh * Sc + s0 + r) * DHc + dh] = f2bf((acc[mt][nt][r] + bv) * QSCALE);
        } else {
          #pragma unroll
          for (int r = 0; r < 4; r++)
            ok[((size_t)bh * Sc + s0 + r) * DHc + dh] = f2bf(acc[mt][nt][r] + bv);
        }
      }
    }
  } else {
    #pragma unroll
    for (int mt = 0; mt < 4; mt++){
      #pragma unroll
      for (int nt = 0; nt < 4; nt++){
        #pragma unroll
        for (int r = 0; r < 4; r++){
          const int gm = mb * 128 + wm * 64 + mt * 16 + lg * 4 + r;
          const int gn = nb * 128 + wn * 64 + nt * 16 + lr;
          float val = acc[mt][nt][r] + bias[gn];
          if (EPI == 1){
            size_t i = (size_t)gm * N + gn;
            outf[i] = val + res[i];
          } else {
            float ge = 0.5f * val * (1.0f + erff(val * 0.70710678118f));
            outb[(size_t)gm * N + gn] = f2bf(ge);
          }
        }
      }
    }
  }
}

// ---------------- Flash attention (no-max-softmax, double-buffered K/V) ----------------
// q: [B*H][S][DH] bf16 PRE-SCALED by QSCALE; k: [B*H][S][DH] bf16;
// vt: [B*H][DH][S] bf16 (pre-transposed); ctx: [B,S,D] bf16
__global__ __launch_bounds__(256) void flash_attn(const ushort* __restrict__ q,
                                                  const ushort* __restrict__ k,
                                                  const ushort* __restrict__ vt,
                                                  ushort* __restrict__ ctx){
  const int bh = blockIdx.y;
  const int q0 = blockIdx.x * 64;
  const int b  = bh >> 4, h = bh & 15;
  const int tid = threadIdx.x, wave = tid >> 6, lane = tid & 63;
  const int lr = lane & 15, lg = lane >> 4;

  // double-buffered 64-row x 64B linear tiles (global_load_lds friendly)
  __shared__ short Kt[2][2][64*32];  // [buf][dh-half][row*32+col]
  __shared__ short Vt[2][2][64*32];  // [buf][kv-half][dhrow*32+col]
  __shared__ short Ps[4][16][68];    // per-wave P tile, 136B stride (conflict-free writes)

  const int sr = tid >> 2, sc = (tid & 3) * 8;
  const ushort* kg = k  + (size_t)bh * Sc * DHc + (size_t)sr * DHc + sc;
  const ushort* vg = vt + (size_t)bh * DHc * Sc + (size_t)sr * Sc  + sc;
  char* Kl0 = (char*)&Kt[0][0][0] + wave * 1024;
  char* Kl1 = (char*)&Kt[0][1][0] + wave * 1024;
  char* Vl0 = (char*)&Vt[0][0][0] + wave * 1024;
  char* Vl1 = (char*)&Vt[0][1][0] + wave * 1024;
  const int BUFB = 2 * 64 * 32 * 2;  // bytes between buf 0 and buf 1

  bf16x8 qf0, qf1;
  {
    const ushort* qp = q + (size_t)bh * Sc * DHc + (size_t)(q0 + wave * 16 + lr) * DHc + lg * 8;
    qf0 = *reinterpret_cast<const bf16x8*>(qp);
    qf1 = *reinterpret_cast<const bf16x8*>(qp + 32);
  }

  f32x4 o[4] = {};
  float lp[4] = {0.f, 0.f, 0.f, 0.f};

  // prologue: stage tile 0 into buf 0
  stage16(kg,      Kl0, lane);
  stage16(kg + 32, Kl1, lane);
  stage16(vg,      Vl0, lane);
  stage16(vg + 32, Vl1, lane);
  __syncthreads();

  for (int kt = 0; kt < Sc / 64; ++kt){
    const int cur = kt & 1;
    // prefetch next tile into the other buffer (hidden under this tile's compute)
    if (kt + 1 < Sc / 64){
      const int nx = (cur ^ 1) * BUFB;
      stage16(kg + (size_t)(kt + 1) * 64 * DHc,      Kl0 + nx, lane);
      stage16(kg + (size_t)(kt + 1) * 64 * DHc + 32, Kl1 + nx, lane);
      stage16(vg + (kt + 1) * 64,                    Vl0 + nx, lane);
      stage16(vg + (kt + 1) * 64 + 32,               Vl1 + nx, lane);
    }

    // S' = (Q*QSCALE) K^T  (exp2 domain, scale pre-folded into Q)
    f32x4 sacc[4];
    __builtin_amdgcn_s_setprio(1);
    #pragma unroll
    for (int nt = 0; nt < 4; nt++){
      bf16x8 b0 = *reinterpret_cast<const bf16x8*>(&Kt[cur][0][(nt*16 + lr)*32 + lg*8]);
      bf16x8 b1 = *reinterpret_cast<const bf16x8*>(&Kt[cur][1][(nt*16 + lr)*32 + lg*8]);
      f32x4 z = {0.f, 0.f, 0.f, 0.f};
      z = __builtin_amdgcn_mfma_f32_16x16x32_bf16(qf0, b0, z, 0, 0, 0);
      z = __builtin_amdgcn_mfma_f32_16x16x32_bf16(qf1, b1, z, 0, 0, 0);
      sacc[nt] = z;
    }
    __builtin_amdgcn_s_setprio(0);

    // P = exp2(clamp(S',16)); accumulate per-lane row-sum partials; pack to LDS
    #pragma unroll
    for (int nt = 0; nt < 4; nt++){
      #pragma unroll
      for (int j = 0; j < 4; j++){
        float p = exp2f(fminf(sacc[nt][j], 16.f));
        lp[j] += p;
        Ps[wave][lg * 4 + j][nt * 16 + lr] = (short)f2bf_fast(p);
      }
    }

    bf16x8 pf0 = *reinterpret_cast<const bf16x8*>(&Ps[wave][lr][lg * 8]);
    bf16x8 pf1 = *reinterpret_cast<const bf16x8*>(&Ps[wave][lr][32 + lg * 8]);
    __builtin_amdgcn_s_setprio(1);
    #pragma unroll
    for (int nt = 0; nt < 4; nt++){
      bf16x8 v0 = *reinterpret_cast<const bf16x8*>(&Vt[cur][0][(nt*16 + lr)*32 + lg*8]);
      bf16x8 v1 = *reinterpret_cast<const bf16x8*>(&Vt[cur][1][(nt*16 + lr)*32 + lg*8]);
      o[nt] = __builtin_amdgcn_mfma_f32_16x16x32_bf16(pf0, v0, o[nt], 0, 0, 0);
      o[nt] = __builtin_amdgcn_mfma_f32_16x16x32_bf16(pf1, v1, o[nt], 0, 0, 0);
    }
    __builtin_amdgcn_s_setprio(0);

    // one barrier per tile: drains prefetch (vmcnt) + ds reads done before re-stage
    __syncthreads();
  }

  // final row-sum reduction across the 16 lr-lanes (lg-groups are xor 1,2,4,8)
  #pragma unroll
  for (int m = 1; m < 16; m <<= 1)
    #pragma unroll
    for (int j = 0; j < 4; j++) lp[j] += __shfl_xor(lp[j], m);

  #pragma unroll
  for (int j = 0; j < 4; j++){
    float inv = 1.0f / lp[j];
    int s = q0 + wave * 16 + lg * 4 + j;
    ushort* op = ctx + ((size_t)b * Sc + s) * Dc + h * DHc;
    #pragma unroll
    for (int nt = 0; nt < 4; nt++)
      op[nt * 16 + lr] = f2bf(o[nt][j] * inv);
  }
}

// ---------------- orchestration ----------------
extern "C" void kernel_launch(void* const* d_in, const int* in_sizes, int n_in,
                              void* d_out, int out_size, void* d_ws, size_t ws_size,
                              hipStream_t stream){
  const float* x     = (const float*)d_in[0];
  const float* ln1_g = (const float*)d_in[1];
  const float* ln1_b = (const float*)d_in[2];
  const float* w_qkv = (const float*)d_in[3];
  const float* b_qkv = (const float*)d_in[4];
  const float* w_out = (const float*)d_in[5];
  const float* b_out = (const float*)d_in[6];
  const float* ln2_g = (const float*)d_in[7];
  const float* ln2_b = (const float*)d_in[8];
  const float* w1    = (const float*)d_in[9];
  const float* b1    = (const float*)d_in[10];
  const float* w2    = (const float*)d_in[11];
  const float* b2    = (const float*)d_in[12];
  float* out = (float*)d_out;

  char* ws = (char*)d_ws;
  size_t off = 0;
  ushort* wqkvT = (ushort*)(ws + off); off += (size_t)3072 * 1024 * 2;
  ushort* woutT = (ushort*)(ws + off); off += (size_t)1024 * 1024 * 2;
  ushort* w1T   = (ushort*)(ws + off); off += (size_t)4096 * 1024 * 2;
  ushort* w2T   = (ushort*)(ws + off); off += (size_t)1024 * 4096 * 2;
  ushort* hln   = (ushort*)(ws + off); off += (size_t)Mc * Dc * 2;
  ushort* qbuf  = (ushort*)(ws + off); off += (size_t)32 * Sc * DHc * 2;
  ushort* kbuf  = (ushort*)(ws + off); off += (size_t)32 * Sc * DHc * 2;
  ushort* vtbuf = (ushort*)(ws + off); off += (size_t)32 * Sc * DHc * 2;
  ushort* ctx   = (ushort*)(ws + off); off += (size_t)Mc * Dc * 2;
  float*  x1    = (float*)(ws + off);  off += (size_t)Mc * Dc * 4;
  ushort* act   = qbuf;  // reuse q/k/vt + ctx region (32 MB), dead after out-proj

  // 1. weight transpose+cast
  tcast<<<dim3(3072 / 32, 1024 / 32), 256, 0, stream>>>(w_qkv, wqkvT, 1024, 3072);
  tcast<<<dim3(1024 / 32, 1024 / 32), 256, 0, stream>>>(w_out, woutT, 1024, 1024);
  tcast<<<dim3(4096 / 32, 1024 / 32), 256, 0, stream>>>(w1,    w1T,   1024, 4096);
  tcast<<<dim3(1024 / 32, 4096 / 32), 256, 0, stream>>>(w2,    w2T,   4096, 1024);

  // 2. LN1
  ln_bf16<<<Mc, 256, 0, stream>>>(x, ln1_g, ln1_b, hln);

  // 3. QKV projection + head scatter (q pre-scaled, v pre-transposed)
  gemm128<0><<<dim3(3072 / 128, Mc / 128), 256, 0, stream>>>(
      hln, wqkvT, b_qkv, nullptr, nullptr, nullptr, qbuf, kbuf, vtbuf, 3072, 1024);

  // 4. attention
  flash_attn<<<dim3(Sc / 64, 32), 256, 0, stream>>>(qbuf, kbuf, vtbuf, ctx);

  // 5. out proj + residual -> x1
  gemm128<1><<<dim3(1024 / 128, Mc / 128), 256, 0, stream>>>(
      ctx, woutT, b_out, x, x1, nullptr, nullptr, nullptr, nullptr, 1024, 1024);

  // 6. LN2
  ln_bf16<<<Mc, 256, 0, stream>>>(x1, ln2_g, ln2_b, hln);

  // 7. MLP up + GELU
  gemm128<2><<<dim3(4096 / 128, Mc / 128), 256, 0, stream>>>(
      hln, w1T, b1, nullptr, nullptr, act, nullptr, nullptr, nullptr, 4096, 1024);

  // 8. MLP down + residual -> out
  gemm128<1><<<dim3(1024 / 128, Mc / 128), 256, 0, stream>>>(
      act, w2T, b2, x1, out, nullptr, nullptr, nullptr, nullptr, 1024, 4096);
}

// Round 4
// 305.829 us; speedup vs baseline: 1.5045x; 1.1378x over previous
//
#include <hip/hip_runtime.h>
#include <hip/hip_bf16.h>
#include <math.h>

#define Bc 2
#define Sc 2048
#define Dc 1024
#define Hc 16
#define DHc 64
#define Mc (Bc*Sc)   // 4096

typedef __attribute__((ext_vector_type(8))) short bf16x8;
typedef __attribute__((ext_vector_type(4))) float f32x4;

// dh^-0.5 * log2(e), folded into Q at the QKV epilogue
#define QSCALE 0.18033688f

__device__ __forceinline__ ushort f2bf(float f){
  union { float f; uint32_t u; } c; c.f = f;
  uint32_t u = c.u;
  return (ushort)((u + 0x7fffu + ((u >> 16) & 1u)) >> 16);
}
// cheap round-half-up bf16 pack (for P > 0); 2 VALU ops
__device__ __forceinline__ ushort f2bf_fast(float f){
  union { float f; uint32_t u; } c; c.f = f;
  return (ushort)((c.u + 0x8000u) >> 16);
}

// async global -> LDS, 16B per lane. lbase must be wave-uniform; HW adds lane*16.
__device__ __forceinline__ void stage16(const void* g, void* lbase, int lane){
#if __has_builtin(__builtin_amdgcn_global_load_lds)
  __builtin_amdgcn_global_load_lds(
      (const __attribute__((address_space(1))) void*)g,
      (__attribute__((address_space(3))) void*)lbase, 16, 0, 0);
#else
  *(int4*)((char*)lbase + lane*16) = *(const int4*)g;
#endif
}

// ---------------- transpose + cast: w[K][N] f32 -> wT[N][K] bf16 ----------------
__global__ __launch_bounds__(256) void tcast(const float* __restrict__ w,
                                             ushort* __restrict__ wt,
                                             int K, int N){
  __shared__ float t[32][33];
  int kb = blockIdx.y * 32, nb = blockIdx.x * 32;
  int tx = threadIdx.x & 31, ty = threadIdx.x >> 5;
  #pragma unroll
  for (int i = 0; i < 4; i++)
    t[ty + 8*i][tx] = w[(size_t)(kb + ty + 8*i) * N + nb + tx];
  __syncthreads();
  #pragma unroll
  for (int i = 0; i < 4; i++)
    wt[(size_t)(nb + ty + 8*i) * K + kb + tx] = f2bf(t[tx][ty + 8*i]);
}

// ---------------- LayerNorm -> bf16 ----------------
__global__ __launch_bounds__(256) void ln_bf16(const float* __restrict__ x,
                                               const float* __restrict__ g,
                                               const float* __restrict__ b,
                                               ushort* __restrict__ out){
  int row = blockIdx.x;
  const float4 xv = reinterpret_cast<const float4*>(x + (size_t)row * Dc)[threadIdx.x];
  float s  = xv.x + xv.y + xv.z + xv.w;
  float sq = xv.x*xv.x + xv.y*xv.y + xv.z*xv.z + xv.w*xv.w;
  #pragma unroll
  for (int m = 1; m < 64; m <<= 1){ s += __shfl_xor(s, m); sq += __shfl_xor(sq, m); }
  __shared__ float ss[4], ssq[4];
  int wv = threadIdx.x >> 6;
  if ((threadIdx.x & 63) == 0){ ss[wv] = s; ssq[wv] = sq; }
  __syncthreads();
  s  = ss[0] + ss[1] + ss[2] + ss[3];
  sq = ssq[0] + ssq[1] + ssq[2] + ssq[3];
  float mu  = s * (1.0f / Dc);
  float var = sq * (1.0f / Dc) - mu * mu;
  float rstd = rsqrtf(var + 1e-5f);
  float4 gv = reinterpret_cast<const float4*>(g)[threadIdx.x];
  float4 bv = reinterpret_cast<const float4*>(b)[threadIdx.x];
  ushort o[4];
  o[0] = f2bf((xv.x - mu) * rstd * gv.x + bv.x);
  o[1] = f2bf((xv.y - mu) * rstd * gv.y + bv.y);
  o[2] = f2bf((xv.z - mu) * rstd * gv.z + bv.z);
  o[3] = f2bf((xv.w - mu) * rstd * gv.w + bv.w);
  *reinterpret_cast<uint2*>(out + (size_t)row * Dc + threadIdx.x * 4) =
      *reinterpret_cast<uint2*>(o);
}

// ---------------- GEMM: C[M,N] = A[M,K](bf16) @ BT[N,K]^T(bf16) + bias ----------------
// Tiles: 128 x BN (BN = 128 or 64). 1-D grid with bijective XCD-chunked swizzle.
// EPI 0: qkv scatter -> q (pre-scaled) / k [B*H][S][DH] bf16, v -> vt [B*H][DH][S]
// EPI 1: out_f32 = acc + bias + res (fp32)
// EPI 2: out_bf16 = gelu_exact(acc + bias)
template<int EPI, int BN>
__global__ __launch_bounds__(256) void gemm128(
    const ushort* __restrict__ A, const ushort* __restrict__ BT,
    const float* __restrict__ bias, const float* __restrict__ res,
    float* __restrict__ outf, ushort* __restrict__ outb,
    ushort* __restrict__ oq, ushort* __restrict__ ok, ushort* __restrict__ ov,
    int N, int K){
  constexpr int NT = BN / 32;      // n-fragments per wave (4 or 2)
  constexpr int WN = BN / 2;       // wave n-extent (64 or 32)
  __shared__ short As[128*32];     // 64B rows, linear for global_load_lds
  __shared__ short Bs[BN*32];

  // bijective XCD-chunked swizzle (gridDim.x % 8 == 0 for all launches)
  const int fid = blockIdx.x;
  const int q8 = gridDim.x >> 3;
  const int id2 = (fid & 7) * q8 + (fid >> 3);
  const int nbx = N / BN;
  const int nb = id2 % nbx, mb = id2 / nbx;

  const int tid = threadIdx.x;
  const int wave = tid >> 6, lane = tid & 63;
  const int wm = wave >> 1, wn = wave & 1;
  const int lr = lane & 15, lg = lane >> 4;

  f32x4 acc[4][NT] = {};

  const int sr = tid >> 2;          // staging row 0..63
  const int sc = (tid & 3) * 8;     // staging col (shorts)
  const ushort* Ag = A  + (size_t)(mb * 128 + sr) * K + sc;
  const ushort* Bg = BT + (size_t)(nb * BN  + sr) * K + sc;
  char* Asw = (char*)As + wave * 1024;
  char* Bsw = (char*)Bs + wave * 1024;
  const int nK = K >> 5;

  for (int kt = 0; kt < nK; ++kt){
    const int ko = kt * 32;
    stage16(Ag + ko,                 Asw,        lane);
    stage16(Ag + (size_t)64*K + ko,  Asw + 4096, lane);
    stage16(Bg + ko,                 Bsw,        lane);
    if (BN == 128)
      stage16(Bg + (size_t)64*K + ko, Bsw + 4096, lane);
    __syncthreads();
    bf16x8 af[4], bfr[NT];
    #pragma unroll
    for (int mt = 0; mt < 4; mt++)
      af[mt] = *reinterpret_cast<const bf16x8*>(&As[(wm*64 + mt*16 + lr)*32 + lg*8]);
    #pragma unroll
    for (int nt = 0; nt < NT; nt++)
      bfr[nt] = *reinterpret_cast<const bf16x8*>(&Bs[(wn*WN + nt*16 + lr)*32 + lg*8]);
    #pragma unroll
    for (int mt = 0; mt < 4; mt++)
      #pragma unroll
      for (int nt = 0; nt < NT; nt++)
        acc[mt][nt] = __builtin_amdgcn_mfma_f32_16x16x32_bf16(af[mt], bfr[nt], acc[mt][nt], 0, 0, 0);
    __syncthreads();
  }

  if (EPI == 0){
    #pragma unroll
    for (int mt = 0; mt < 4; mt++){
      const int gm0 = mb * 128 + wm * 64 + mt * 16 + lg * 4;
      const int bb = gm0 >> 11, s0 = gm0 & 2047;
      #pragma unroll
      for (int nt = 0; nt < NT; nt++){
        const int gn = nb * BN + wn * WN + nt * 16 + lr;
        const float bv = bias[gn];
        const int p = gn >> 10, d = gn & 1023;
        const int hh = d >> 6, dh = d & 63;
        const int bh = bb * Hc + hh;
        if (p == 2){
          ushort pk[4];
          #pragma unroll
          for (int r = 0; r < 4; r++) pk[r] = f2bf(acc[mt][nt][r] + bv);
          *reinterpret_cast<uint2*>(ov + ((size_t)bh * DHc + dh) * Sc + s0) =
              *reinterpret_cast<uint2*>(pk);
        } else if (p == 0){
          #pragma unroll
          for (int r = 0; r < 4; r++)
            oq[((size_t)bh * Sc + s0 + r) * DHc + dh] = f2bf((acc[mt][nt][r] + bv) * QSCALE);
        } else {
          #pragma unroll
          for (int r = 0; r < 4; r++)
            ok[((size_t)bh * Sc + s0 + r) * DHc + dh] = f2bf(acc[mt][nt][r] + bv);
        }
      }
    }
  } else {
    #pragma unroll
    for (int mt = 0; mt < 4; mt++){
      #pragma unroll
      for (int nt = 0; nt < NT; nt++){
        #pragma unroll
        for (int r = 0; r < 4; r++){
          const int gm = mb * 128 + wm * 64 + mt * 16 + lg * 4 + r;
          const int gn = nb * BN + wn * WN + nt * 16 + lr;
          float val = acc[mt][nt][r] + bias[gn];
          if (EPI == 1){
            size_t i = (size_t)gm * N + gn;
            outf[i] = val + res[i];
          } else {
            float ge = 0.5f * val * (1.0f + erff(val * 0.70710678118f));
            outb[(size_t)gm * N + gn] = f2bf(ge);
          }
        }
      }
    }
  }
}

// ---------------- Flash attention (no-max softmax, K dbuf + V reg-staged) ----------------
// q: [B*H][S][DH] bf16 PRE-SCALED by QSCALE; k: [B*H][S][DH] bf16;
// vt: [B*H][DH][S] bf16 (pre-transposed); ctx: [B,S,D] bf16
__global__ __launch_bounds__(256) void flash_attn(const ushort* __restrict__ q,
                                                  const ushort* __restrict__ k,
                                                  const ushort* __restrict__ vt,
                                                  ushort* __restrict__ ctx){
  const int bh = blockIdx.y;
  const int q0 = blockIdx.x * 64;
  const int b  = bh >> 4, h = bh & 15;
  const int tid = threadIdx.x, wave = tid >> 6, lane = tid & 63;
  const int lr = lane & 15, lg = lane >> 4;

  __shared__ short Kt[2][2][64*32];  // [buf][dh-half][row*32+col]  16 KB
  __shared__ short Vt[2][64*32];     // [kv-half][dhrow*32+col]      8 KB (single buf)
  __shared__ short Ps[4][16][68];    // per-wave P tile             8.7 KB

  const int sr = tid >> 2, sc = (tid & 3) * 8;
  const ushort* kg = k  + (size_t)bh * Sc * DHc + (size_t)sr * DHc + sc;
  const ushort* vg = vt + (size_t)bh * DHc * Sc + (size_t)sr * Sc  + sc;
  char* Kl0 = (char*)&Kt[0][0][0] + wave * 1024;
  char* Kl1 = (char*)&Kt[0][1][0] + wave * 1024;
  char* Vl0 = (char*)&Vt[0][0]    + wave * 1024;
  char* Vl1 = (char*)&Vt[1][0]    + wave * 1024;
  const int KBUFB = 2 * 64 * 32 * 2;   // bytes between K buf 0 and buf 1

  bf16x8 qf0, qf1;
  {
    const ushort* qp = q + (size_t)bh * Sc * DHc + (size_t)(q0 + wave * 16 + lr) * DHc + lg * 8;
    qf0 = *reinterpret_cast<const bf16x8*>(qp);
    qf1 = *reinterpret_cast<const bf16x8*>(qp + 32);
  }

  f32x4 o[4] = {};
  float lp[4] = {0.f, 0.f, 0.f, 0.f};
  constexpr int NTILES = Sc / 64;

  // prologue: stage tile 0 (K into buf0, V into single buf)
  stage16(kg,      Kl0, lane);
  stage16(kg + 32, Kl1, lane);
  stage16(vg,      Vl0, lane);
  stage16(vg + 32, Vl1, lane);
  __syncthreads();

  for (int kt = 0; kt < NTILES; ++kt){
    const int cur = kt & 1;
    int4 vr0, vr1;
    if (kt + 1 < NTILES){
      // K(kt+1): async to the other K buffer (lands by the next barrier)
      const int nx = (cur ^ 1) * KBUFB;
      stage16(kg + (size_t)(kt + 1) * 64 * DHc,      Kl0 + nx, lane);
      stage16(kg + (size_t)(kt + 1) * 64 * DHc + 32, Kl1 + nx, lane);
      // V(kt+1): global -> registers; written to LDS after the barrier
      vr0 = *reinterpret_cast<const int4*>(vg + (kt + 1) * 64);
      vr1 = *reinterpret_cast<const int4*>(vg + (kt + 1) * 64 + 32);
    }

    // S' = (Q*QSCALE) K^T  (exp2 domain)
    f32x4 sacc[4];
    __builtin_amdgcn_s_setprio(1);
    #pragma unroll
    for (int nt = 0; nt < 4; nt++){
      bf16x8 b0 = *reinterpret_cast<const bf16x8*>(&Kt[cur][0][(nt*16 + lr)*32 + lg*8]);
      bf16x8 b1 = *reinterpret_cast<const bf16x8*>(&Kt[cur][1][(nt*16 + lr)*32 + lg*8]);
      f32x4 z = {0.f, 0.f, 0.f, 0.f};
      z = __builtin_amdgcn_mfma_f32_16x16x32_bf16(qf0, b0, z, 0, 0, 0);
      z = __builtin_amdgcn_mfma_f32_16x16x32_bf16(qf1, b1, z, 0, 0, 0);
      sacc[nt] = z;
    }
    __builtin_amdgcn_s_setprio(0);

    // P = exp2(S'); per-lane row-sum partials; pack to LDS
    #pragma unroll
    for (int nt = 0; nt < 4; nt++){
      #pragma unroll
      for (int j = 0; j < 4; j++){
        float p = exp2f(sacc[nt][j]);
        lp[j] += p;
        Ps[wave][lg * 4 + j][nt * 16 + lr] = (short)f2bf_fast(p);
      }
    }

    bf16x8 pf0 = *reinterpret_cast<const bf16x8*>(&Ps[wave][lr][lg * 8]);
    bf16x8 pf1 = *reinterpret_cast<const bf16x8*>(&Ps[wave][lr][32 + lg * 8]);
    __builtin_amdgcn_s_setprio(1);
    #pragma unroll
    for (int nt = 0; nt < 4; nt++){
      bf16x8 v0 = *reinterpret_cast<const bf16x8*>(&Vt[0][(nt*16 + lr)*32 + lg*8]);
      bf16x8 v1 = *reinterpret_cast<const bf16x8*>(&Vt[1][(nt*16 + lr)*32 + lg*8]);
      o[nt] = __builtin_amdgcn_mfma_f32_16x16x32_bf16(pf0, v0, o[nt], 0, 0, 0);
      o[nt] = __builtin_amdgcn_mfma_f32_16x16x32_bf16(pf1, v1, o[nt], 0, 0, 0);
    }
    __builtin_amdgcn_s_setprio(0);

    __syncthreads();              // all waves done reading Vt & Kt[cur]
    if (kt + 1 < NTILES){
      // V(kt+1) regs -> LDS (loads arrived during this tile's compute)
      *reinterpret_cast<int4*>((char*)&Vt[0][0] + tid * 16) = vr0;
      *reinterpret_cast<int4*>((char*)&Vt[1][0] + tid * 16) = vr1;
      __syncthreads();            // V visible; K(kt+1) drained by barrier waitcnt
    }
  }

  // final row-sum reduction across the 4 lane-groups (xor 16,32 not needed: groups are lg)
  #pragma unroll
  for (int m = 1; m < 16; m <<= 1)
    #pragma unroll
    for (int j = 0; j < 4; j++) lp[j] += __shfl_xor(lp[j], m);

  #pragma unroll
  for (int j = 0; j < 4; j++){
    float inv = 1.0f / lp[j];
    int s = q0 + wave * 16 + lg * 4 + j;
    ushort* op = ctx + ((size_t)b * Sc + s) * Dc + h * DHc;
    #pragma unroll
    for (int nt = 0; nt < 4; nt++)
      op[nt * 16 + lr] = f2bf(o[nt][j] * inv);
  }
}

// ---------------- orchestration ----------------
extern "C" void kernel_launch(void* const* d_in, const int* in_sizes, int n_in,
                              void* d_out, int out_size, void* d_ws, size_t ws_size,
                              hipStream_t stream){
  const float* x     = (const float*)d_in[0];
  const float* ln1_g = (const float*)d_in[1];
  const float* ln1_b = (const float*)d_in[2];
  const float* w_qkv = (const float*)d_in[3];
  const float* b_qkv = (const float*)d_in[4];
  const float* w_out = (const float*)d_in[5];
  const float* b_out = (const float*)d_in[6];
  const float* ln2_g = (const float*)d_in[7];
  const float* ln2_b = (const float*)d_in[8];
  const float* w1    = (const float*)d_in[9];
  const float* b1    = (const float*)d_in[10];
  const float* w2    = (const float*)d_in[11];
  const float* b2    = (const float*)d_in[12];
  float* out = (float*)d_out;

  char* ws = (char*)d_ws;
  size_t off = 0;
  ushort* wqkvT = (ushort*)(ws + off); off += (size_t)3072 * 1024 * 2;
  ushort* woutT = (ushort*)(ws + off); off += (size_t)1024 * 1024 * 2;
  ushort* w1T   = (ushort*)(ws + off); off += (size_t)4096 * 1024 * 2;
  ushort* w2T   = (ushort*)(ws + off); off += (size_t)1024 * 4096 * 2;
  ushort* hln   = (ushort*)(ws + off); off += (size_t)Mc * Dc * 2;
  ushort* qbuf  = (ushort*)(ws + off); off += (size_t)32 * Sc * DHc * 2;
  ushort* kbuf  = (ushort*)(ws + off); off += (size_t)32 * Sc * DHc * 2;
  ushort* vtbuf = (ushort*)(ws + off); off += (size_t)32 * Sc * DHc * 2;
  ushort* ctx   = (ushort*)(ws + off); off += (size_t)Mc * Dc * 2;
  float*  x1    = (float*)(ws + off);  off += (size_t)Mc * Dc * 4;
  ushort* act   = qbuf;  // reuse q/k/vt + ctx region (32 MB), dead after out-proj

  // 1. weight transpose+cast
  tcast<<<dim3(3072 / 32, 1024 / 32), 256, 0, stream>>>(w_qkv, wqkvT, 1024, 3072);
  tcast<<<dim3(1024 / 32, 1024 / 32), 256, 0, stream>>>(w_out, woutT, 1024, 1024);
  tcast<<<dim3(4096 / 32, 1024 / 32), 256, 0, stream>>>(w1,    w1T,   1024, 4096);
  tcast<<<dim3(1024 / 32, 4096 / 32), 256, 0, stream>>>(w2,    w2T,   4096, 1024);

  // 2. LN1
  ln_bf16<<<Mc, 256, 0, stream>>>(x, ln1_g, ln1_b, hln);

  // 3. QKV projection + head scatter (q pre-scaled, v pre-transposed)  grid 24*32=768
  gemm128<0,128><<<(3072/128) * (Mc/128), 256, 0, stream>>>(
      hln, wqkvT, b_qkv, nullptr, nullptr, nullptr, qbuf, kbuf, vtbuf, 3072, 1024);

  // 4. attention
  flash_attn<<<dim3(Sc / 64, 32), 256, 0, stream>>>(qbuf, kbuf, vtbuf, ctx);

  // 5. out proj + residual -> x1   grid 16*32=512 (BN=64)
  gemm128<1,64><<<(1024/64) * (Mc/128), 256, 0, stream>>>(
      ctx, woutT, b_out, x, x1, nullptr, nullptr, nullptr, nullptr, 1024, 1024);

  // 6. LN2
  ln_bf16<<<Mc, 256, 0, stream>>>(x1, ln2_g, ln2_b, hln);

  // 7. MLP up + GELU   grid 32*32=1024
  gemm128<2,128><<<(4096/128) * (Mc/128), 256, 0, stream>>>(
      hln, w1T, b1, nullptr, nullptr, act, nullptr, nullptr, nullptr, 4096, 1024);

  // 8. MLP down + residual -> out   grid 16*32=512 (BN=64)
  gemm128<1,64><<<(1024/64) * (Mc/128), 256, 0, stream>>>(
      act, w2T, b2, x1, out, nullptr, nullptr, nullptr, nullptr, 1024, 4096);
}

// Round 5
// 289.701 us; speedup vs baseline: 1.5883x; 1.0557x over previous
//
#include <hip/hip_runtime.h>
#include <hip/hip_bf16.h>
#include <math.h>

#define Bc 2
#define Sc 2048
#define Dc 1024
#define Hc 16
#define DHc 64
#define Mc (Bc*Sc)   // 4096

typedef __attribute__((ext_vector_type(8))) short bf16x8;
typedef __attribute__((ext_vector_type(4))) float f32x4;

// dh^-0.5 * log2(e), folded into Q at the QKV epilogue
#define QSCALE 0.18033688f

__device__ __forceinline__ ushort f2bf(float f){
  union { float f; uint32_t u; } c; c.f = f;
  uint32_t u = c.u;
  return (ushort)((u + 0x7fffu + ((u >> 16) & 1u)) >> 16);
}
// cheap round-half-up bf16 pack (for P > 0); 2 VALU ops
__device__ __forceinline__ ushort f2bf_fast(float f){
  union { float f; uint32_t u; } c; c.f = f;
  return (ushort)((c.u + 0x8000u) >> 16);
}

// async global -> LDS, 16B per lane. lbase must be wave-uniform; HW adds lane*16.
__device__ __forceinline__ void stage16(const void* g, void* lbase, int lane){
#if __has_builtin(__builtin_amdgcn_global_load_lds)
  __builtin_amdgcn_global_load_lds(
      (const __attribute__((address_space(1))) void*)g,
      (__attribute__((address_space(3))) void*)lbase, 16, 0, 0);
#else
  *(int4*)((char*)lbase + lane*16) = *(const int4*)g;
#endif
}

// ---------------- transpose + cast: w[K][N] f32 -> wT[N][K] bf16 ----------------
__global__ __launch_bounds__(256) void tcast(const float* __restrict__ w,
                                             ushort* __restrict__ wt,
                                             int K, int N){
  __shared__ float t[32][33];
  int kb = blockIdx.y * 32, nb = blockIdx.x * 32;
  int tx = threadIdx.x & 31, ty = threadIdx.x >> 5;
  #pragma unroll
  for (int i = 0; i < 4; i++)
    t[ty + 8*i][tx] = w[(size_t)(kb + ty + 8*i) * N + nb + tx];
  __syncthreads();
  #pragma unroll
  for (int i = 0; i < 4; i++)
    wt[(size_t)(nb + ty + 8*i) * K + kb + tx] = f2bf(t[tx][ty + 8*i]);
}

// ---------------- LayerNorm -> bf16 ----------------
__global__ __launch_bounds__(256) void ln_bf16(const float* __restrict__ x,
                                               const float* __restrict__ g,
                                               const float* __restrict__ b,
                                               ushort* __restrict__ out){
  int row = blockIdx.x;
  const float4 xv = reinterpret_cast<const float4*>(x + (size_t)row * Dc)[threadIdx.x];
  float s  = xv.x + xv.y + xv.z + xv.w;
  float sq = xv.x*xv.x + xv.y*xv.y + xv.z*xv.z + xv.w*xv.w;
  #pragma unroll
  for (int m = 1; m < 64; m <<= 1){ s += __shfl_xor(s, m); sq += __shfl_xor(sq, m); }
  __shared__ float ss[4], ssq[4];
  int wv = threadIdx.x >> 6;
  if ((threadIdx.x & 63) == 0){ ss[wv] = s; ssq[wv] = sq; }
  __syncthreads();
  s  = ss[0] + ss[1] + ss[2] + ss[3];
  sq = ssq[0] + ssq[1] + ssq[2] + ssq[3];
  float mu  = s * (1.0f / Dc);
  float var = sq * (1.0f / Dc) - mu * mu;
  float rstd = rsqrtf(var + 1e-5f);
  float4 gv = reinterpret_cast<const float4*>(g)[threadIdx.x];
  float4 bv = reinterpret_cast<const float4*>(b)[threadIdx.x];
  ushort o[4];
  o[0] = f2bf((xv.x - mu) * rstd * gv.x + bv.x);
  o[1] = f2bf((xv.y - mu) * rstd * gv.y + bv.y);
  o[2] = f2bf((xv.z - mu) * rstd * gv.z + bv.z);
  o[3] = f2bf((xv.w - mu) * rstd * gv.w + bv.w);
  *reinterpret_cast<uint2*>(out + (size_t)row * Dc + threadIdx.x * 4) =
      *reinterpret_cast<uint2*>(o);
}

// ---------------- GEMM: C[M,N] = A[M,K](bf16) @ BT[N,K]^T(bf16) + bias ----------------
// 128 x BN tiles, BK=32, double-buffered LDS (T3 2-phase), 2-bit XOR swizzle
// (pre-swizzled global source + swizzled ds_read; 8-way -> 4-way conflicts).
// EPI 0: qkv scatter -> q (pre-scaled) / k [B*H][S][DH] bf16, v -> vt [B*H][DH][S]
// EPI 1: out_f32 = acc + bias + res (fp32)
// EPI 2: out_bf16 = gelu_exact(acc + bias)
template<int EPI, int BN>
__global__ __launch_bounds__(256) void gemm128(
    const ushort* __restrict__ A, const ushort* __restrict__ BT,
    const float* __restrict__ bias, const float* __restrict__ res,
    float* __restrict__ outf, ushort* __restrict__ outb,
    ushort* __restrict__ oq, ushort* __restrict__ ok, ushort* __restrict__ ov,
    int N, int K){
  constexpr int NT = BN / 32;      // n-fragments per wave (4 or 2)
  constexpr int WN = BN / 2;       // wave n-extent (64 or 32)
  __shared__ short As[2][128*32];  // 64B rows, linear dest for global_load_lds
  __shared__ short Bs[2][BN*32];

  // bijective XCD-chunked swizzle (gridDim.x % 8 == 0 for all launches)
  const int fid = blockIdx.x;
  const int q8 = gridDim.x >> 3;
  const int id2 = (fid & 7) * q8 + (fid >> 3);
  const int nbx = N / BN;
  const int nb = id2 % nbx, mb = id2 / nbx;

  const int tid = threadIdx.x;
  const int wave = tid >> 6, lane = tid & 63;
  const int wm = wave >> 1, wn = wave & 1;
  const int lr = lane & 15, lg = lane >> 4;

  f32x4 acc[4][NT] = {};

  // staging: row sr, source col pre-swizzled by ((sr&3)<<3) shorts (16B granules)
  const int sr = tid >> 2;
  const int sc = ((tid & 3) * 8) ^ ((sr & 3) * 8);
  const ushort* Ag = A  + (size_t)(mb * 128 + sr) * K + sc;
  const ushort* Bg = BT + (size_t)(nb * BN  + sr) * K + sc;
  const int nK = K >> 5;

  // prologue: stage tile 0 into buf 0
  {
    char* Ab = (char*)&As[0][0] + wave * 1024;
    char* Bb = (char*)&Bs[0][0] + wave * 1024;
    stage16(Ag,                 Ab,        lane);
    stage16(Ag + (size_t)64*K,  Ab + 4096, lane);
    stage16(Bg,                 Bb,        lane);
    if (BN == 128) stage16(Bg + (size_t)64*K, Bb + 4096, lane);
  }
  __syncthreads();

  const int rsz = (lr & 3) * 8;   // read-side XOR (shorts)

  for (int kt = 0; kt < nK; ++kt){
    const int cur = kt & 1;
    if (kt + 1 < nK){   // stage next tile into other buffer (hidden under compute)
      const int ko = (kt + 1) * 32;
      char* Ab = (char*)&As[cur ^ 1][0] + wave * 1024;
      char* Bb = (char*)&Bs[cur ^ 1][0] + wave * 1024;
      stage16(Ag + ko,                 Ab,        lane);
      stage16(Ag + (size_t)64*K + ko,  Ab + 4096, lane);
      stage16(Bg + ko,                 Bb,        lane);
      if (BN == 128) stage16(Bg + (size_t)64*K + ko, Bb + 4096, lane);
    }
    bf16x8 af[4], bfr[NT];
    #pragma unroll
    for (int mt = 0; mt < 4; mt++)
      af[mt] = *reinterpret_cast<const bf16x8*>(
          &As[cur][(wm*64 + mt*16 + lr)*32 + ((lg*8) ^ rsz)]);
    #pragma unroll
    for (int nt = 0; nt < NT; nt++)
      bfr[nt] = *reinterpret_cast<const bf16x8*>(
          &Bs[cur][(wn*WN + nt*16 + lr)*32 + ((lg*8) ^ rsz)]);
    #pragma unroll
    for (int mt = 0; mt < 4; mt++)
      #pragma unroll
      for (int nt = 0; nt < NT; nt++)
        acc[mt][nt] = __builtin_amdgcn_mfma_f32_16x16x32_bf16(af[mt], bfr[nt], acc[mt][nt], 0, 0, 0);
    __syncthreads();   // reads of buf[cur] done; stage into buf[cur^1] drained
  }

  if (EPI == 0){
    #pragma unroll
    for (int mt = 0; mt < 4; mt++){
      const int gm0 = mb * 128 + wm * 64 + mt * 16 + lg * 4;
      const int bb = gm0 >> 11, s0 = gm0 & 2047;
      #pragma unroll
      for (int nt = 0; nt < NT; nt++){
        const int gn = nb * BN + wn * WN + nt * 16 + lr;
        const float bv = bias[gn];
        const int p = gn >> 10, d = gn & 1023;
        const int hh = d >> 6, dh = d & 63;
        const int bh = bb * Hc + hh;
        if (p == 2){
          ushort pk[4];
          #pragma unroll
          for (int r = 0; r < 4; r++) pk[r] = f2bf(acc[mt][nt][r] + bv);
          *reinterpret_cast<uint2*>(ov + ((size_t)bh * DHc + dh) * Sc + s0) =
              *reinterpret_cast<uint2*>(pk);
        } else if (p == 0){
          #pragma unroll
          for (int r = 0; r < 4; r++)
            oq[((size_t)bh * Sc + s0 + r) * DHc + dh] = f2bf((acc[mt][nt][r] + bv) * QSCALE);
        } else {
          #pragma unroll
          for (int r = 0; r < 4; r++)
            ok[((size_t)bh * Sc + s0 + r) * DHc + dh] = f2bf(acc[mt][nt][r] + bv);
        }
      }
    }
  } else {
    #pragma unroll
    for (int mt = 0; mt < 4; mt++){
      #pragma unroll
      for (int nt = 0; nt < NT; nt++){
        #pragma unroll
        for (int r = 0; r < 4; r++){
          const int gm = mb * 128 + wm * 64 + mt * 16 + lg * 4 + r;
          const int gn = nb * BN + wn * WN + nt * 16 + lr;
          float val = acc[mt][nt][r] + bias[gn];
          if (EPI == 1){
            size_t i = (size_t)gm * N + gn;
            outf[i] = val + res[i];
          } else {
            float ge = 0.5f * val * (1.0f + erff(val * 0.70710678118f));
            outb[(size_t)gm * N + gn] = f2bf(ge);
          }
        }
      }
    }
  }
}

// ---------------- Flash attention (no-max softmax, K dbuf + V reg-staged) ----------------
// K/V tiles: [64][64 shorts] = 128B rows, XOR-swizzled (byte ^= (row&7)<<4) via
// pre-swizzled global source + swizzled ds_read (both-sides, rule 21).
// q: [B*H][S][DH] bf16 PRE-SCALED by QSCALE; k: [B*H][S][DH]; vt: [B*H][DH][S];
// ctx: [B,S,D] bf16
__global__ __launch_bounds__(256) void flash_attn(const ushort* __restrict__ q,
                                                  const ushort* __restrict__ k,
                                                  const ushort* __restrict__ vt,
                                                  ushort* __restrict__ ctx){
  const int bh = blockIdx.y;
  const int q0 = blockIdx.x * 64;
  const int b  = bh >> 4, h = bh & 15;
  const int tid = threadIdx.x, wave = tid >> 6, lane = tid & 63;
  const int lr = lane & 15, lg = lane >> 4;

  __shared__ short Kt[2][64*64];   // [buf][kv*64 + dh], 128B rows, swizzled   16 KB
  __shared__ short Vt[64*64];      // [dh*64 + kv],      128B rows, swizzled    8 KB
  __shared__ short Ps[4][16][68];  // per-wave P tile                          8.5 KB

  // ---- K staging geometry (global_load_lds, linear dest, pre-swizzled source)
  // site s in {0,1}: wave w, lane l -> LDS row s*32 + w*8 + (l>>3), granule l&7.
  const int g8  = lane & 7;
  const int kr0 = wave * 8 + (lane >> 3);          // site-0 row; site-1 row = kr0+32
  const int kcol = (g8 ^ (kr0 & 7)) * 8;           // shorts; (kr0+32)&7 == kr0&7
  const ushort* kg0 = k + (size_t)bh * Sc * DHc + (size_t)kr0 * DHc + kcol;
  const ushort* kg1 = kg0 + 32 * DHc;
  char* Kl = (char*)&Kt[0][0] + wave * 1024;       // site0; site1 = +4096; buf1 = +8192
  const int KBUFB = 64 * 64 * 2;

  // ---- V staging geometry (reg-staged: 256 threads x 2 int4 = 8 KB)
  const int vrow = tid >> 3, vg8 = tid & 7;
  const int vcol = (vg8 ^ (vrow & 7)) * 8;         // shorts; (vrow+32)&7 == vrow&7
  const ushort* vg0 = vt + (size_t)bh * DHc * Sc + (size_t)vrow * Sc + vcol;
  const ushort* vg1 = vg0 + (size_t)32 * Sc;

  bf16x8 qf0, qf1;
  {
    const ushort* qp = q + (size_t)bh * Sc * DHc + (size_t)(q0 + wave * 16 + lr) * DHc + lg * 8;
    qf0 = *reinterpret_cast<const bf16x8*>(qp);
    qf1 = *reinterpret_cast<const bf16x8*>(qp + 32);
  }

  f32x4 o[4] = {};
  float lp[4] = {0.f, 0.f, 0.f, 0.f};
  constexpr int NTILES = Sc / 64;

  // prologue: tile 0 (K async into buf0, V via regs)
  stage16(kg0, Kl,        lane);
  stage16(kg1, Kl + 4096, lane);
  {
    int4 w0 = *reinterpret_cast<const int4*>(vg0);
    int4 w1 = *reinterpret_cast<const int4*>(vg1);
    *reinterpret_cast<int4*>((char*)&Vt[0] + tid * 16)        = w0;
    *reinterpret_cast<int4*>((char*)&Vt[0] + 4096 + tid * 16) = w1;
  }
  __syncthreads();

  const int swz = (lr & 7) * 8;   // read-side XOR (shorts), row&7 == lr&7

  for (int kt = 0; kt < NTILES; ++kt){
    const int cur = kt & 1;
    int4 vr0, vr1;
    if (kt + 1 < NTILES){
      // K(kt+1): async into other buffer
      const int nx = (cur ^ 1) * KBUFB;
      stage16(kg0 + (size_t)(kt + 1) * 64 * DHc, Kl + nx,        lane);
      stage16(kg1 + (size_t)(kt + 1) * 64 * DHc, Kl + nx + 4096, lane);
      // V(kt+1): global -> regs (consumed after the barrier)
      vr0 = *reinterpret_cast<const int4*>(vg0 + (kt + 1) * 64);
      vr1 = *reinterpret_cast<const int4*>(vg1 + (kt + 1) * 64);
    }

    // S' = (Q*QSCALE) K^T  (exp2 domain)
    f32x4 sacc[4];
    __builtin_amdgcn_s_setprio(1);
    #pragma unroll
    for (int nt = 0; nt < 4; nt++){
      const int rb = (nt * 16 + lr) * 64;
      bf16x8 b0 = *reinterpret_cast<const bf16x8*>(&Kt[cur][rb + ((lg * 8) ^ swz)]);
      bf16x8 b1 = *reinterpret_cast<const bf16x8*>(&Kt[cur][rb + ((32 + lg * 8) ^ swz)]);
      f32x4 z = {0.f, 0.f, 0.f, 0.f};
      z = __builtin_amdgcn_mfma_f32_16x16x32_bf16(qf0, b0, z, 0, 0, 0);
      z = __builtin_amdgcn_mfma_f32_16x16x32_bf16(qf1, b1, z, 0, 0, 0);
      sacc[nt] = z;
    }
    __builtin_amdgcn_s_setprio(0);

    // P = exp2(S'); per-lane row-sum partials; pack to LDS
    #pragma unroll
    for (int nt = 0; nt < 4; nt++){
      #pragma unroll
      for (int j = 0; j < 4; j++){
        float p = exp2f(sacc[nt][j]);
        lp[j] += p;
        Ps[wave][lg * 4 + j][nt * 16 + lr] = (short)f2bf_fast(p);
      }
    }

    bf16x8 pf0 = *reinterpret_cast<const bf16x8*>(&Ps[wave][lr][lg * 8]);
    bf16x8 pf1 = *reinterpret_cast<const bf16x8*>(&Ps[wave][lr][32 + lg * 8]);
    __builtin_amdgcn_s_setprio(1);
    #pragma unroll
    for (int nt = 0; nt < 4; nt++){
      const int rb = (nt * 16 + lr) * 64;
      bf16x8 v0 = *reinterpret_cast<const bf16x8*>(&Vt[rb + ((lg * 8) ^ swz)]);
      bf16x8 v1 = *reinterpret_cast<const bf16x8*>(&Vt[rb + ((32 + lg * 8) ^ swz)]);
      o[nt] = __builtin_amdgcn_mfma_f32_16x16x32_bf16(pf0, v0, o[nt], 0, 0, 0);
      o[nt] = __builtin_amdgcn_mfma_f32_16x16x32_bf16(pf1, v1, o[nt], 0, 0, 0);
    }
    __builtin_amdgcn_s_setprio(0);

    __syncthreads();              // all waves done reading Vt & Kt[cur]; K(kt+1) drained
    if (kt + 1 < NTILES){
      *reinterpret_cast<int4*>((char*)&Vt[0] + tid * 16)        = vr0;
      *reinterpret_cast<int4*>((char*)&Vt[0] + 4096 + tid * 16) = vr1;
      __syncthreads();            // V(kt+1) visible
    }
  }

  // final row-sum reduction across the 16 lr-lanes
  #pragma unroll
  for (int m = 1; m < 16; m <<= 1)
    #pragma unroll
    for (int j = 0; j < 4; j++) lp[j] += __shfl_xor(lp[j], m);

  #pragma unroll
  for (int j = 0; j < 4; j++){
    float inv = 1.0f / lp[j];
    int s = q0 + wave * 16 + lg * 4 + j;
    ushort* op = ctx + ((size_t)b * Sc + s) * Dc + h * DHc;
    #pragma unroll
    for (int nt = 0; nt < 4; nt++)
      op[nt * 16 + lr] = f2bf(o[nt][j] * inv);
  }
}

// ---------------- orchestration ----------------
extern "C" void kernel_launch(void* const* d_in, const int* in_sizes, int n_in,
                              void* d_out, int out_size, void* d_ws, size_t ws_size,
                              hipStream_t stream){
  const float* x     = (const float*)d_in[0];
  const float* ln1_g = (const float*)d_in[1];
  const float* ln1_b = (const float*)d_in[2];
  const float* w_qkv = (const float*)d_in[3];
  const float* b_qkv = (const float*)d_in[4];
  const float* w_out = (const float*)d_in[5];
  const float* b_out = (const float*)d_in[6];
  const float* ln2_g = (const float*)d_in[7];
  const float* ln2_b = (const float*)d_in[8];
  const float* w1    = (const float*)d_in[9];
  const float* b1    = (const float*)d_in[10];
  const float* w2    = (const float*)d_in[11];
  const float* b2    = (const float*)d_in[12];
  float* out = (float*)d_out;

  char* ws = (char*)d_ws;
  size_t off = 0;
  ushort* wqkvT = (ushort*)(ws + off); off += (size_t)3072 * 1024 * 2;
  ushort* woutT = (ushort*)(ws + off); off += (size_t)1024 * 1024 * 2;
  ushort* w1T   = (ushort*)(ws + off); off += (size_t)4096 * 1024 * 2;
  ushort* w2T   = (ushort*)(ws + off); off += (size_t)1024 * 4096 * 2;
  ushort* hln   = (ushort*)(ws + off); off += (size_t)Mc * Dc * 2;
  ushort* qbuf  = (ushort*)(ws + off); off += (size_t)32 * Sc * DHc * 2;
  ushort* kbuf  = (ushort*)(ws + off); off += (size_t)32 * Sc * DHc * 2;
  ushort* vtbuf = (ushort*)(ws + off); off += (size_t)32 * Sc * DHc * 2;
  ushort* ctx   = (ushort*)(ws + off); off += (size_t)Mc * Dc * 2;
  float*  x1    = (float*)(ws + off);  off += (size_t)Mc * Dc * 4;
  ushort* act   = qbuf;  // reuse q/k/vt + ctx region (32 MB), dead after out-proj

  // 1. weight transpose+cast
  tcast<<<dim3(3072 / 32, 1024 / 32), 256, 0, stream>>>(w_qkv, wqkvT, 1024, 3072);
  tcast<<<dim3(1024 / 32, 1024 / 32), 256, 0, stream>>>(w_out, woutT, 1024, 1024);
  tcast<<<dim3(4096 / 32, 1024 / 32), 256, 0, stream>>>(w1,    w1T,   1024, 4096);
  tcast<<<dim3(1024 / 32, 4096 / 32), 256, 0, stream>>>(w2,    w2T,   4096, 1024);

  // 2. LN1
  ln_bf16<<<Mc, 256, 0, stream>>>(x, ln1_g, ln1_b, hln);

  // 3. QKV projection + head scatter (q pre-scaled, v pre-transposed)  grid 768
  gemm128<0,128><<<(3072/128) * (Mc/128), 256, 0, stream>>>(
      hln, wqkvT, b_qkv, nullptr, nullptr, nullptr, qbuf, kbuf, vtbuf, 3072, 1024);

  // 4. attention
  flash_attn<<<dim3(Sc / 64, 32), 256, 0, stream>>>(qbuf, kbuf, vtbuf, ctx);

  // 5. out proj + residual -> x1   grid 512 (BN=64)
  gemm128<1,64><<<(1024/64) * (Mc/128), 256, 0, stream>>>(
      ctx, woutT, b_out, x, x1, nullptr, nullptr, nullptr, nullptr, 1024, 1024);

  // 6. LN2
  ln_bf16<<<Mc, 256, 0, stream>>>(x1, ln2_g, ln2_b, hln);

  // 7. MLP up + GELU   grid 1024
  gemm128<2,128><<<(4096/128) * (Mc/128), 256, 0, stream>>>(
      hln, w1T, b1, nullptr, nullptr, act, nullptr, nullptr, nullptr, 4096, 1024);

  // 8. MLP down + residual -> out   grid 512 (BN=64)
  gemm128<1,64><<<(1024/64) * (Mc/128), 256, 0, stream>>>(
      act, w2T, b2, x1, out, nullptr, nullptr, nullptr, nullptr, 1024, 4096);
}